// Round 8
// baseline (262.172 us; speedup 1.0000x reference)
//
#include <hip/hip_runtime.h>

#define NN 50000
#define NE 1600000
#define DD 128
#define HH 128
#define CC 10
#define GG 512
#define LRELU_A 0.05f
#define BN_EPS 1e-5f

#define TT 256          // tiles for counting sort
#define EPT (NE / TT)   // 6250 edges per tile
#define HALF 25000      // node half-range per LDS pass
#define SB ((NN + 255) / 256)  // 196 scan blocks
#define KNODE 8         // nodes per wave in aggregate

typedef unsigned int u32;
typedef unsigned short u16;

__device__ __forceinline__ u16 f2bf(float f) {
    u32 u = __float_as_uint(f);
    u32 r = u + 0x7FFFu + ((u >> 16) & 1u);
    return (u16)(r >> 16);
}

// ---------------- stats: global sum & sumsq of x_in ----------------
__global__ __launch_bounds__(256) void k_stats(const float* __restrict__ x,
                                               double* __restrict__ st) {
    const int M4 = NN * DD / 4;
    double s = 0.0, ss = 0.0;
    for (int i = blockIdx.x * blockDim.x + threadIdx.x; i < M4;
         i += gridDim.x * blockDim.x) {
        float4 v = reinterpret_cast<const float4*>(x)[i];
        s  += (double)v.x + (double)v.y + (double)v.z + (double)v.w;
        ss += (double)v.x * v.x + (double)v.y * v.y + (double)v.z * v.z +
              (double)v.w * v.w;
    }
    for (int d = 32; d; d >>= 1) { s += __shfl_down(s, d); ss += __shfl_down(ss, d); }
    __shared__ double ls[4], lss[4];
    int lane = threadIdx.x & 63, w = threadIdx.x >> 6;
    if (lane == 0) { ls[w] = s; lss[w] = ss; }
    __syncthreads();
    if (threadIdx.x == 0) {
        s  = ls[0] + ls[1] + ls[2] + ls[3];
        ss = lss[0] + lss[1] + lss[2] + lss[3];
        atomicAdd(&st[0], s);
        atomicAdd(&st[1], ss);
    }
}

// ---------------- finalize stats + per-output-row weight sums ----------------
__global__ __launch_bounds__(128) void k_finalize(const float* __restrict__ fc_w,
                                                  const double* __restrict__ st,
                                                  float* __restrict__ wsum,
                                                  float* __restrict__ musig) {
    int c = threadIdx.x;
    float s = 0.f;
    for (int k = 0; k < DD; ++k) s += fc_w[c * DD + k];
    wsum[c] = s;
    if (c == 0) {
        double M = (double)NN * DD;
        double mean = st[0] / M;
        double var  = (st[1] - st[0] * st[0] / M) / (M - 1.0);  // ddof=1
        musig[0] = (float)mean;
        musig[1] = (float)(1.0 / sqrt(var));
    }
}

// ---------------- transpose fc_w -> wt[k][c] (global, 64 KB) ----------------
__global__ __launch_bounds__(256) void k_wt(const float* __restrict__ w,
                                            float* __restrict__ wt) {
    int i = blockIdx.x * 256 + threadIdx.x;  // i = k*128 + c
    int k = i >> 7, c = i & 127;
    wt[i] = w[c * DD + k];
}

// ------- tile histogram: cnt_t[t][n] = #edges of tile t with src==n -------
// LDS: 2 x u16 packed per u32 over a 25000-node half-range (50 KB).
__global__ __launch_bounds__(256) void k_thist(const int* __restrict__ src,
                                               u16* __restrict__ cnt_t) {
    __shared__ u32 h[HALF / 2];
    int t = blockIdx.x, tid = threadIdx.x;
    int e0 = t * EPT;
    int s[25];
    #pragma unroll
    for (int i = 0; i < 25; ++i) {
        int el = i * 256 + tid;
        s[i] = (el < EPT) ? src[e0 + el] : -1;
    }
    for (int half = 0; half < 2; ++half) {
        int lo = half * HALF;
        for (int i = tid; i < HALF / 2; i += 256) h[i] = 0;
        __syncthreads();
        #pragma unroll
        for (int i = 0; i < 25; ++i) {
            int n = s[i] - lo;
            if (n >= 0 && n < HALF)
                atomicAdd(&h[n >> 1], (n & 1) ? 65536u : 1u);
        }
        __syncthreads();
        u32* out = reinterpret_cast<u32*>(cnt_t + (size_t)t * NN + lo);
        for (int i = tid; i < HALF / 2; i += 256) out[i] = h[i];
        __syncthreads();
    }
}

// --- per-node prefix over tiles: rel[t][n]; block-local scan of degrees ---
// off[n] = exclusive prefix within block; part[b] = block total.
__global__ __launch_bounds__(256) void k_rel(const u16* __restrict__ cnt_t,
                                             u16* __restrict__ rel,
                                             int* __restrict__ off,
                                             int* __restrict__ part) {
    int b = blockIdx.x, t = threadIdx.x;
    int n = b * 256 + t;
    int run = 0;
    if (n < NN) {
        for (int tt = 0; tt < TT; ++tt) {
            int c = cnt_t[(size_t)tt * NN + n];
            rel[(size_t)tt * NN + n] = (u16)run;
            run += c;
        }
    }
    __shared__ int sm[256];
    sm[t] = run;
    __syncthreads();
    int v = run;
    for (int d = 1; d < 256; d <<= 1) {
        int x = 0;
        if (t >= d) x = sm[t - d];
        __syncthreads();
        if (t >= d) sm[t] += x;
        __syncthreads();
    }
    if (n < NN) off[n] = sm[t] - v;  // block-exclusive prefix
    if (t == 255) part[b] = sm[255];
}

// ---------------- scan the 196 block partials (one tiny block) ----------------
__global__ __launch_bounds__(256) void k_scan2(int* __restrict__ part) {
    __shared__ int sm[256];
    int t = threadIdx.x;
    int v = (t < SB) ? part[t] : 0;
    sm[t] = v;
    __syncthreads();
    for (int d = 1; d < 256; d <<= 1) {
        int x = 0;
        if (t >= d) x = sm[t - d];
        __syncthreads();
        if (t >= d) sm[t] += x;
        __syncthreads();
    }
    if (t < SB) part[t] = sm[t] - v;  // exclusive
}

// ---------------- uniform add: off[n] += part[b]; off[NN] = NE ----------------
__global__ __launch_bounds__(256) void k_add(int* __restrict__ off,
                                             const int* __restrict__ part) {
    int b = blockIdx.x, t = threadIdx.x;
    int n = b * 256 + t;
    if (n < NN) off[n] += part[b];
    if (b == 0 && t == 0) off[NN] = NE;
}

// ------- scatter (atomic-free): slot = off[n] + rel[t][n] + LDS local rank ---
__global__ __launch_bounds__(256) void k_scatter2(const int* __restrict__ src,
                                                  const int* __restrict__ dst,
                                                  const int* __restrict__ off,
                                                  const u16* __restrict__ rel,
                                                  int* __restrict__ dst_s) {
    __shared__ u32 h[HALF / 2];
    int t = blockIdx.x, tid = threadIdx.x;
    int e0 = t * EPT;
    int s[25], d[25];
    #pragma unroll
    for (int i = 0; i < 25; ++i) {
        int el = i * 256 + tid;
        if (el < EPT) { s[i] = src[e0 + el]; d[i] = dst[e0 + el]; }
        else s[i] = -1;
    }
    const u16* relt = rel + (size_t)t * NN;
    for (int half = 0; half < 2; ++half) {
        int lo = half * HALF;
        for (int i = tid; i < HALF / 2; i += 256) h[i] = 0;
        __syncthreads();
        #pragma unroll
        for (int i = 0; i < 25; ++i) {
            int n = s[i] - lo;
            if (n >= 0 && n < HALF) {
                u32 old = atomicAdd(&h[n >> 1], (n & 1) ? 65536u : 1u);
                int lrank = (n & 1) ? (int)(old >> 16) : (int)(old & 0xFFFFu);
                int node = s[i];
                int p = off[node] + (int)relt[node] + lrank;
                dst_s[p] = d[i];
            }
        }
        __syncthreads();
    }
}

// ------ z = x_std @ fc_w^T, fused: z bf16, s1=z@a1, s2=z@a2 ------
#define PADX 132
__global__ __launch_bounds__(256, 4) void k_gemm(const float* __restrict__ x,
                                                 const float* __restrict__ wt,
                                                 const float* __restrict__ wsum,
                                                 const float* __restrict__ musig,
                                                 const float* __restrict__ a1,
                                                 const float* __restrict__ a2,
                                                 u32* __restrict__ zbf,
                                                 float* __restrict__ s1,
                                                 float* __restrict__ s2) {
    __shared__ float xs[64][PADX];  // ~34 KB -> 4 blocks/CU
    int tid = threadIdx.x;
    int row0 = blockIdx.x * 64;

    for (int i = tid; i < 64 * 32; i += 256) {
        int r = i >> 5;
        int m = i & 31;
        int gr = row0 + r;
        float4 v = (gr < NN) ? reinterpret_cast<const float4*>(x)[gr * 32 + m]
                             : make_float4(0.f, 0.f, 0.f, 0.f);
        *reinterpret_cast<float4*>(&xs[r][m << 2]) = v;
    }
    __syncthreads();

    int trow = tid >> 4, tcol = tid & 15;
    float acc[4][8];
    #pragma unroll
    for (int i = 0; i < 4; ++i)
        #pragma unroll
        for (int j = 0; j < 8; ++j) acc[i][j] = 0.f;

    const float4* wt4 = reinterpret_cast<const float4*>(wt);
    for (int k = 0; k < 128; k += 4) {
        float4 xv[4];
        #pragma unroll
        for (int i = 0; i < 4; ++i)
            xv[i] = *reinterpret_cast<const float4*>(&xs[trow * 4 + i][k]);
        #pragma unroll
        for (int kk = 0; kk < 4; ++kk) {
            float4 w0 = wt4[(k + kk) * 32 + tcol * 2];
            float4 w1 = wt4[(k + kk) * 32 + tcol * 2 + 1];
            #pragma unroll
            for (int i = 0; i < 4; ++i) {
                float a = (kk == 0) ? xv[i].x
                        : (kk == 1) ? xv[i].y
                        : (kk == 2) ? xv[i].z : xv[i].w;
                acc[i][0] += a * w0.x; acc[i][1] += a * w0.y;
                acc[i][2] += a * w0.z; acc[i][3] += a * w0.w;
                acc[i][4] += a * w1.x; acc[i][5] += a * w1.y;
                acc[i][6] += a * w1.z; acc[i][7] += a * w1.w;
            }
        }
    }

    float mu = musig[0], isig = musig[1];
    int c0 = tcol * 8;
    float4 a10 = *reinterpret_cast<const float4*>(&a1[c0]);
    float4 a11 = *reinterpret_cast<const float4*>(&a1[c0 + 4]);
    float4 a20 = *reinterpret_cast<const float4*>(&a2[c0]);
    float4 a21 = *reinterpret_cast<const float4*>(&a2[c0 + 4]);
    float ws0x = wsum[c0 + 0], ws0y = wsum[c0 + 1], ws0z = wsum[c0 + 2], ws0w = wsum[c0 + 3];
    float ws1x = wsum[c0 + 4], ws1y = wsum[c0 + 5], ws1z = wsum[c0 + 6], ws1w = wsum[c0 + 7];

    float p1[4], p2[4];
    #pragma unroll
    for (int i = 0; i < 4; ++i) {
        int gr = row0 + trow * 4 + i;
        float4 o0, o1;
        o0.x = (acc[i][0] - mu * ws0x) * isig;
        o0.y = (acc[i][1] - mu * ws0y) * isig;
        o0.z = (acc[i][2] - mu * ws0z) * isig;
        o0.w = (acc[i][3] - mu * ws0w) * isig;
        o1.x = (acc[i][4] - mu * ws1x) * isig;
        o1.y = (acc[i][5] - mu * ws1y) * isig;
        o1.z = (acc[i][6] - mu * ws1z) * isig;
        o1.w = (acc[i][7] - mu * ws1w) * isig;
        p1[i] = o0.x * a10.x + o0.y * a10.y + o0.z * a10.z + o0.w * a10.w +
                o1.x * a11.x + o1.y * a11.y + o1.z * a11.z + o1.w * a11.w;
        p2[i] = o0.x * a20.x + o0.y * a20.y + o0.z * a20.z + o0.w * a20.w +
                o1.x * a21.x + o1.y * a21.y + o1.z * a21.z + o1.w * a21.w;
        if (gr < NN) {
            uint4 pk;
            pk.x = ((u32)f2bf(o0.y) << 16) | f2bf(o0.x);
            pk.y = ((u32)f2bf(o0.w) << 16) | f2bf(o0.z);
            pk.z = ((u32)f2bf(o1.y) << 16) | f2bf(o1.x);
            pk.w = ((u32)f2bf(o1.w) << 16) | f2bf(o1.z);
            // row = 128 bf16 = 64 u32; thread covers u32 [tcol*4, tcol*4+4)
            *reinterpret_cast<uint4*>(&zbf[gr * 64 + tcol * 4]) = pk;
        }
    }
    // reduce p1/p2 across the 16 tcol lanes (same trow group)
    #pragma unroll
    for (int d = 8; d; d >>= 1) {
        #pragma unroll
        for (int i = 0; i < 4; ++i) {
            p1[i] += __shfl_down(p1[i], d, 16);
            p2[i] += __shfl_down(p2[i], d, 16);
        }
    }
    if (tcol == 0) {
        #pragma unroll
        for (int i = 0; i < 4; ++i) {
            int gr = row0 + trow * 4 + i;
            if (gr < NN) { s1[gr] = p1[i]; s2[gr] = p2[i]; }
        }
    }
}

// --- aggregate v3: quad-edge dwordx4 gathers (16 lanes per row) ---
// lane = (sub<<4)|col : sub = edge-of-quad (0..3), col = 16B chunk (0..15).
// One uint4 load fetches 4 edges' rows; acc[8] folded via shfl_xor(16,32).
__global__ __launch_bounds__(256) void k_aggregate(const u32* __restrict__ zbf,
                                                   const float* __restrict__ s1,
                                                   const float* __restrict__ s2,
                                                   const int* __restrict__ off,
                                                   const int* __restrict__ dst_s,
                                                   const int* __restrict__ idx,
                                                   float* __restrict__ pooled) {
    int wave = (blockIdx.x * 256 + threadIdx.x) >> 6;
    int lane = threadIdx.x & 63;
    int n0 = wave * KNODE;
    if (n0 >= NN) return;
    int n1 = n0 + KNODE;
    if (n1 > NN) n1 = NN;
    int sub = lane >> 4;
    int col = lane & 15;
    const uint4* zbf4 = reinterpret_cast<const uint4*>(zbf);

    float pool[8];
    #pragma unroll
    for (int j = 0; j < 8; ++j) pool[j] = 0.f;
    int curg = idx[n0];

    for (int node = n0; node < n1; ++node) {
        int g = idx[node];
        if (g != curg) {
            if (lane < 16) {
                #pragma unroll
                for (int j = 0; j < 8; ++j)
                    atomicAdd(&pooled[curg * HH + col * 8 + j], pool[j]);
            }
            #pragma unroll
            for (int j = 0; j < 8; ++j) pool[j] = 0.f;
            curg = g;
        }
        int j0 = off[node], j1 = off[node + 1];
        float s1n = s1[node];
        float acc[8];
        #pragma unroll
        for (int j = 0; j < 8; ++j) acc[j] = 0.f;
        float hsl = 0.f;

        for (int b = j0; b < j1; b += 64) {
            int cnt = j1 - b;
            if (cnt > 64) cnt = 64;
            // lane-parallel attention weights: lane l owns edge b+l
            int jj = b + ((lane < cnt) ? lane : 0);
            int dl = dst_s[jj];
            float ev = s1n + s2[dl];
            ev = (ev >= 0.f) ? ev : LRELU_A * ev;
            float hl = (lane < cnt) ? __expf(ev) : 0.f;
            hsl += hl;
            // quad-edge gather: lanes of sub-group `sub` read row of edge k+sub
            for (int k = 0; k < cnt; k += 4) {
                int dk = __shfl(dl, k + sub);
                float hk = __shfl(hl, k + sub);
                uint4 u = zbf4[(dk << 4) | col];
                acc[0] += hk * __uint_as_float(u.x << 16);
                acc[1] += hk * __uint_as_float(u.x & 0xFFFF0000u);
                acc[2] += hk * __uint_as_float(u.y << 16);
                acc[3] += hk * __uint_as_float(u.y & 0xFFFF0000u);
                acc[4] += hk * __uint_as_float(u.z << 16);
                acc[5] += hk * __uint_as_float(u.z & 0xFFFF0000u);
                acc[6] += hk * __uint_as_float(u.w << 16);
                acc[7] += hk * __uint_as_float(u.w & 0xFFFF0000u);
            }
        }
        // fold the 4 edge sub-groups (lane bits 4,5)
        #pragma unroll
        for (int j = 0; j < 8; ++j) {
            acc[j] += __shfl_xor(acc[j], 16);
            acc[j] += __shfl_xor(acc[j], 32);
        }
        // softmax denominator: full-wave reduce
        float hs = hsl;
        #pragma unroll
        for (int d = 32; d; d >>= 1) hs += __shfl_xor(hs, d);
        float inv = (hs > 0.f) ? 1.f / hs : 0.f;
        #pragma unroll
        for (int j = 0; j < 8; ++j) pool[j] += fmaxf(acc[j] * inv, 0.f);
    }
    if (lane < 16) {
        #pragma unroll
        for (int j = 0; j < 8; ++j)
            atomicAdd(&pooled[curg * HH + col * 8 + j], pool[j]);
    }
}

// ---------------- batchnorm stats -> scale/shift ----------------
__global__ __launch_bounds__(512) void k_bn(const float* __restrict__ pooled,
                                            const float* __restrict__ gamma,
                                            const float* __restrict__ beta,
                                            float* __restrict__ scale,
                                            float* __restrict__ shift) {
    __shared__ float sm[512], sm2[512];
    int f = threadIdx.x & 127, q = threadIdx.x >> 7;
    float s = 0.f, ss = 0.f;
    for (int g = q; g < GG; g += 4) {
        float v = pooled[g * HH + f];
        s += v;
        ss += v * v;
    }
    sm[threadIdx.x] = s;
    sm2[threadIdx.x] = ss;
    __syncthreads();
    if (q == 0) {
        s  = sm[f] + sm[f + 128] + sm[f + 256] + sm[f + 384];
        ss = sm2[f] + sm2[f + 128] + sm2[f + 256] + sm2[f + 384];
        float mean = s / GG;
        float var  = ss / GG - mean * mean;  // biased (jnp.var default)
        float sc = gamma[f] * rsqrtf(var + BN_EPS);
        scale[f] = sc;
        shift[f] = beta[f] - mean * sc;
    }
}

// ---------------- head: BN affine -> fc1+relu -> fc2 -> log_softmax --------
__global__ __launch_bounds__(128) void k_head(const float* __restrict__ pooled,
                                              const float* __restrict__ scale,
                                              const float* __restrict__ shift,
                                              const float* __restrict__ fc1w,
                                              const float* __restrict__ fc1b,
                                              const float* __restrict__ fc2w,
                                              const float* __restrict__ fc2b,
                                              float* __restrict__ out) {
    __shared__ __align__(16) float xb[128];
    __shared__ __align__(16) float h1[128];
    __shared__ float lg[16];
    int g = blockIdx.x;
    int t = threadIdx.x;
    xb[t] = pooled[g * HH + t] * scale[t] + shift[t];
    __syncthreads();
    float acc = 0.f;
    const float4* wr = reinterpret_cast<const float4*>(&fc1w[t * HH]);
    #pragma unroll 8
    for (int k = 0; k < 32; ++k) {
        float4 w4 = wr[k];
        float4 xv = *reinterpret_cast<const float4*>(&xb[k * 4]);
        acc += w4.x * xv.x + w4.y * xv.y + w4.z * xv.z + w4.w * xv.w;
    }
    acc += fc1b[t];
    h1[t] = (acc > 0.f) ? acc : 0.f;
    __syncthreads();
    if (t < CC) {
        float a = 0.f;
        const float4* w2 = reinterpret_cast<const float4*>(&fc2w[t * HH]);
        #pragma unroll 8
        for (int k = 0; k < 32; ++k) {
            float4 w4 = w2[k];
            float4 hv = *reinterpret_cast<const float4*>(&h1[k * 4]);
            a += w4.x * hv.x + w4.y * hv.y + w4.z * hv.z + w4.w * hv.w;
        }
        lg[t] = a + fc2b[t];
    }
    __syncthreads();
    if (t == 0) {
        float mx = lg[0];
        for (int c = 1; c < CC; ++c) mx = fmaxf(mx, lg[c]);
        float se = 0.f;
        for (int c = 0; c < CC; ++c) se += __expf(lg[c] - mx);
        float lse = mx + logf(se);
        for (int c = 0; c < CC; ++c) out[g * CC + c] = lg[c] - lse;
    }
}

// ---------------- launch ----------------
extern "C" void kernel_launch(void* const* d_in, const int* in_sizes, int n_in,
                              void* d_out, int out_size, void* d_ws, size_t ws_size,
                              hipStream_t stream) {
    const float* x_in  = (const float*)d_in[0];
    const int*   eidx  = (const int*)d_in[1];
    const int*   src   = eidx;
    const int*   dst   = eidx + NE;
    const int*   idx   = (const int*)d_in[2];
    const float* fc_w  = (const float*)d_in[3];
    const float* a1    = (const float*)d_in[4];
    const float* a2    = (const float*)d_in[5];
    const float* fc1w  = (const float*)d_in[6];
    const float* fc1b  = (const float*)d_in[7];
    const float* fc2w  = (const float*)d_in[8];
    const float* fc2b  = (const float*)d_in[9];
    const float* gamma = (const float*)d_in[10];
    const float* beta  = (const float*)d_in[11];
    float* out = (float*)d_out;

    char* p = (char*)d_ws;
    auto alloc = [&](size_t bytes) {
        char* r = p;
        p += (bytes + 255) & ~(size_t)255;
        return r;
    };
    double* st     = (double*)alloc(4 * sizeof(double));
    float*  wsum   = (float*)alloc(HH * sizeof(float));
    float*  musig  = (float*)alloc(4 * sizeof(float));
    float*  scale  = (float*)alloc(HH * sizeof(float));
    float*  shift  = (float*)alloc(HH * sizeof(float));
    float*  wt     = (float*)alloc((size_t)DD * HH * sizeof(float));
    u16*    cnt_t  = (u16*)alloc((size_t)TT * NN * sizeof(u16));
    u16*    rel    = (u16*)alloc((size_t)TT * NN * sizeof(u16));
    int*    part   = (int*)alloc(SB * sizeof(int));
    int*    off    = (int*)alloc((NN + 1) * sizeof(int));
    int*    dst_s  = (int*)alloc((size_t)NE * sizeof(int));
    u32*    zbf    = (u32*)alloc((size_t)NN * (HH / 2) * sizeof(u32));
    float*  s1     = (float*)alloc(NN * sizeof(float));
    float*  s2     = (float*)alloc(NN * sizeof(float));
    float*  pooled = (float*)alloc((size_t)GG * HH * sizeof(float));

    hipMemsetAsync(st, 0, 4 * sizeof(double), stream);
    hipMemsetAsync(pooled, 0, (size_t)GG * HH * sizeof(float), stream);

    k_stats<<<1024, 256, 0, stream>>>(x_in, st);
    k_finalize<<<1, 128, 0, stream>>>(fc_w, st, wsum, musig);
    k_wt<<<(DD * HH) / 256, 256, 0, stream>>>(fc_w, wt);
    k_thist<<<TT, 256, 0, stream>>>(src, cnt_t);
    k_rel<<<SB, 256, 0, stream>>>(cnt_t, rel, off, part);
    k_scan2<<<1, 256, 0, stream>>>(part);
    k_add<<<SB, 256, 0, stream>>>(off, part);
    k_gemm<<<(NN + 63) / 64, 256, 0, stream>>>(x_in, wt, wsum, musig, a1, a2,
                                               zbf, s1, s2);
    k_scatter2<<<TT, 256, 0, stream>>>(src, dst, off, rel, dst_s);
    int nwaves = (NN + KNODE - 1) / KNODE;          // 6250
    int nblocks = (nwaves + 3) / 4;                 // 4 waves per 256-thr block
    k_aggregate<<<nblocks, 256, 0, stream>>>(zbf, s1, s2, off, dst_s, idx, pooled);
    k_bn<<<1, 512, 0, stream>>>(pooled, gamma, beta, scale, shift);
    k_head<<<GG, 128, 0, stream>>>(pooled, scale, shift, fc1w, fc1b, fc2w, fc2b, out);
}

// Round 9
// 250.793 us; speedup vs baseline: 1.0454x; 1.0454x over previous
//
#include <hip/hip_runtime.h>

#define NN 50000
#define NE 1600000
#define DD 128
#define HH 128
#define CC 10
#define GG 512
#define LRELU_A 0.05f
#define BN_EPS 1e-5f

#define TT 256          // tiles for counting sort
#define EPT (NE / TT)   // 6250 edges per tile
#define HALF 25000      // node half-range per LDS pass
#define SB ((NN + 255) / 256)  // 196 scan blocks
#define KNODE 8         // nodes per wave in aggregate

typedef unsigned int u32;
typedef unsigned short u16;
typedef unsigned char u8;

__device__ __forceinline__ u16 f2bf(float f) {
    u32 u = __float_as_uint(f);
    u32 r = u + 0x7FFFu + ((u >> 16) & 1u);
    return (u16)(r >> 16);
}

// ---------------- stats: global sum & sumsq of x_in ----------------
__global__ __launch_bounds__(256) void k_stats(const float* __restrict__ x,
                                               double* __restrict__ st) {
    const int M4 = NN * DD / 4;
    double s = 0.0, ss = 0.0;
    for (int i = blockIdx.x * blockDim.x + threadIdx.x; i < M4;
         i += gridDim.x * blockDim.x) {
        float4 v = reinterpret_cast<const float4*>(x)[i];
        s  += (double)v.x + (double)v.y + (double)v.z + (double)v.w;
        ss += (double)v.x * v.x + (double)v.y * v.y + (double)v.z * v.z +
              (double)v.w * v.w;
    }
    for (int d = 32; d; d >>= 1) { s += __shfl_down(s, d); ss += __shfl_down(ss, d); }
    __shared__ double ls[4], lss[4];
    int lane = threadIdx.x & 63, w = threadIdx.x >> 6;
    if (lane == 0) { ls[w] = s; lss[w] = ss; }
    __syncthreads();
    if (threadIdx.x == 0) {
        s  = ls[0] + ls[1] + ls[2] + ls[3];
        ss = lss[0] + lss[1] + lss[2] + lss[3];
        atomicAdd(&st[0], s);
        atomicAdd(&st[1], ss);
    }
}

// ---------------- finalize stats + per-output-row weight sums ----------------
__global__ __launch_bounds__(128) void k_finalize(const float* __restrict__ fc_w,
                                                  const double* __restrict__ st,
                                                  float* __restrict__ wsum,
                                                  float* __restrict__ musig) {
    int c = threadIdx.x;
    float s = 0.f;
    for (int k = 0; k < DD; ++k) s += fc_w[c * DD + k];
    wsum[c] = s;
    if (c == 0) {
        double M = (double)NN * DD;
        double mean = st[0] / M;
        double var  = (st[1] - st[0] * st[0] / M) / (M - 1.0);  // ddof=1
        musig[0] = (float)mean;
        musig[1] = (float)(1.0 / sqrt(var));
    }
}

// ---------------- transpose fc_w -> wt[k][c] (global, 64 KB) ----------------
__global__ __launch_bounds__(256) void k_wt(const float* __restrict__ w,
                                            float* __restrict__ wt) {
    int i = blockIdx.x * 256 + threadIdx.x;  // i = k*128 + c
    int k = i >> 7, c = i & 127;
    wt[i] = w[c * DD + k];
}

// ------- tile histogram + local ranks: cnt_t[t][n] (u8), lrank[e] (u8) -------
// LDS: 2 x u16 packed per u32 over a 25000-node half-range (50 KB).
__global__ __launch_bounds__(256) void k_thist(const int* __restrict__ src,
                                               u8* __restrict__ cnt_t,
                                               u8* __restrict__ lrank) {
    __shared__ u32 h[HALF / 2];
    int t = blockIdx.x, tid = threadIdx.x;
    int e0 = t * EPT;
    int s[25];
    #pragma unroll
    for (int i = 0; i < 25; ++i) {
        int el = i * 256 + tid;
        s[i] = (el < EPT) ? src[e0 + el] : -1;
    }
    for (int half = 0; half < 2; ++half) {
        int lo = half * HALF;
        for (int i = tid; i < HALF / 2; i += 256) h[i] = 0;
        __syncthreads();
        #pragma unroll
        for (int i = 0; i < 25; ++i) {
            int n = s[i] - lo;
            if (n >= 0 && n < HALF) {
                u32 old = atomicAdd(&h[n >> 1], (n & 1) ? 65536u : 1u);
                u32 r = (n & 1) ? (old >> 16) : (old & 0xFFFFu);
                lrank[e0 + i * 256 + tid] = (u8)r;  // any in-tile order is valid
            }
        }
        __syncthreads();
        // pack 4 u8 counts per u32 store
        u32* outp = reinterpret_cast<u32*>(cnt_t + (size_t)t * NN + lo);
        for (int i = tid; i < HALF / 4; i += 256) {
            u32 a = h[2 * i], b = h[2 * i + 1];
            outp[i] = (a & 0xFFu) | ((a >> 8) & 0xFF00u) |
                      ((b & 0xFFu) << 16) | (((b >> 16) & 0xFFu) << 24);
        }
        __syncthreads();
    }
}

// --- per-node prefix over tiles: rel[t][n] (u8); block-local degree scan ---
__global__ __launch_bounds__(256) void k_rel(const u8* __restrict__ cnt_t,
                                             u8* __restrict__ rel,
                                             int* __restrict__ off,
                                             int* __restrict__ part) {
    int b = blockIdx.x, t = threadIdx.x;
    int n = b * 256 + t;
    int run = 0;
    if (n < NN) {
        for (int tt = 0; tt < TT; ++tt) {
            int c = cnt_t[(size_t)tt * NN + n];
            rel[(size_t)tt * NN + n] = (u8)run;
            run += c;
        }
    }
    __shared__ int sm[256];
    sm[t] = run;
    __syncthreads();
    int v = run;
    for (int d = 1; d < 256; d <<= 1) {
        int x = 0;
        if (t >= d) x = sm[t - d];
        __syncthreads();
        if (t >= d) sm[t] += x;
        __syncthreads();
    }
    if (n < NN) off[n] = sm[t] - v;  // block-exclusive prefix
    if (t == 255) part[b] = sm[255];
}

// ---------------- scan the 196 block partials (one tiny block) ----------------
__global__ __launch_bounds__(256) void k_scan2(int* __restrict__ part) {
    __shared__ int sm[256];
    int t = threadIdx.x;
    int v = (t < SB) ? part[t] : 0;
    sm[t] = v;
    __syncthreads();
    for (int d = 1; d < 256; d <<= 1) {
        int x = 0;
        if (t >= d) x = sm[t - d];
        __syncthreads();
        if (t >= d) sm[t] += x;
        __syncthreads();
    }
    if (t < SB) part[t] = sm[t] - v;  // exclusive
}

// ---------------- uniform add: off[n] += part[b]; off[NN] = NE ----------------
__global__ __launch_bounds__(256) void k_add(int* __restrict__ off,
                                             const int* __restrict__ part) {
    int b = blockIdx.x, t = threadIdx.x;
    int n = b * 256 + t;
    if (n < NN) off[n] += part[b];
    if (b == 0 && t == 0) off[NN] = NE;
}

// ------- scatter (no LDS, no atomics): p = off[n] + rel[t][n] + lrank[e] ----
__global__ __launch_bounds__(256) void k_scatter3(const int* __restrict__ src,
                                                  const int* __restrict__ dst,
                                                  const int* __restrict__ off,
                                                  const u8* __restrict__ rel,
                                                  const u8* __restrict__ lrank,
                                                  int* __restrict__ dst_s) {
    for (int e = blockIdx.x * 256 + threadIdx.x; e < NE;
         e += gridDim.x * 256) {
        int t = e / EPT;
        int n = src[e];
        int p = off[n] + (int)rel[(size_t)t * NN + n] + (int)lrank[e];
        dst_s[p] = dst[e];
    }
}

// ------ z = x_std @ fc_w^T, fused: z bf16, s1=z@a1, s2=z@a2 ------
#define PADX 132
__global__ __launch_bounds__(256, 4) void k_gemm(const float* __restrict__ x,
                                                 const float* __restrict__ wt,
                                                 const float* __restrict__ wsum,
                                                 const float* __restrict__ musig,
                                                 const float* __restrict__ a1,
                                                 const float* __restrict__ a2,
                                                 u32* __restrict__ zbf,
                                                 float* __restrict__ s1,
                                                 float* __restrict__ s2) {
    __shared__ float xs[64][PADX];  // ~34 KB -> 4 blocks/CU
    int tid = threadIdx.x;
    int row0 = blockIdx.x * 64;

    for (int i = tid; i < 64 * 32; i += 256) {
        int r = i >> 5;
        int m = i & 31;
        int gr = row0 + r;
        float4 v = (gr < NN) ? reinterpret_cast<const float4*>(x)[gr * 32 + m]
                             : make_float4(0.f, 0.f, 0.f, 0.f);
        *reinterpret_cast<float4*>(&xs[r][m << 2]) = v;
    }
    __syncthreads();

    int trow = tid >> 4, tcol = tid & 15;
    float acc[4][8];
    #pragma unroll
    for (int i = 0; i < 4; ++i)
        #pragma unroll
        for (int j = 0; j < 8; ++j) acc[i][j] = 0.f;

    const float4* wt4 = reinterpret_cast<const float4*>(wt);
    for (int k = 0; k < 128; k += 4) {
        float4 xv[4];
        #pragma unroll
        for (int i = 0; i < 4; ++i)
            xv[i] = *reinterpret_cast<const float4*>(&xs[trow * 4 + i][k]);
        #pragma unroll
        for (int kk = 0; kk < 4; ++kk) {
            float4 w0 = wt4[(k + kk) * 32 + tcol * 2];
            float4 w1 = wt4[(k + kk) * 32 + tcol * 2 + 1];
            #pragma unroll
            for (int i = 0; i < 4; ++i) {
                float a = (kk == 0) ? xv[i].x
                        : (kk == 1) ? xv[i].y
                        : (kk == 2) ? xv[i].z : xv[i].w;
                acc[i][0] += a * w0.x; acc[i][1] += a * w0.y;
                acc[i][2] += a * w0.z; acc[i][3] += a * w0.w;
                acc[i][4] += a * w1.x; acc[i][5] += a * w1.y;
                acc[i][6] += a * w1.z; acc[i][7] += a * w1.w;
            }
        }
    }

    float mu = musig[0], isig = musig[1];
    int c0 = tcol * 8;
    float4 a10 = *reinterpret_cast<const float4*>(&a1[c0]);
    float4 a11 = *reinterpret_cast<const float4*>(&a1[c0 + 4]);
    float4 a20 = *reinterpret_cast<const float4*>(&a2[c0]);
    float4 a21 = *reinterpret_cast<const float4*>(&a2[c0 + 4]);
    float ws0x = wsum[c0 + 0], ws0y = wsum[c0 + 1], ws0z = wsum[c0 + 2], ws0w = wsum[c0 + 3];
    float ws1x = wsum[c0 + 4], ws1y = wsum[c0 + 5], ws1z = wsum[c0 + 6], ws1w = wsum[c0 + 7];

    float p1[4], p2[4];
    #pragma unroll
    for (int i = 0; i < 4; ++i) {
        int gr = row0 + trow * 4 + i;
        float4 o0, o1;
        o0.x = (acc[i][0] - mu * ws0x) * isig;
        o0.y = (acc[i][1] - mu * ws0y) * isig;
        o0.z = (acc[i][2] - mu * ws0z) * isig;
        o0.w = (acc[i][3] - mu * ws0w) * isig;
        o1.x = (acc[i][4] - mu * ws1x) * isig;
        o1.y = (acc[i][5] - mu * ws1y) * isig;
        o1.z = (acc[i][6] - mu * ws1z) * isig;
        o1.w = (acc[i][7] - mu * ws1w) * isig;
        p1[i] = o0.x * a10.x + o0.y * a10.y + o0.z * a10.z + o0.w * a10.w +
                o1.x * a11.x + o1.y * a11.y + o1.z * a11.z + o1.w * a11.w;
        p2[i] = o0.x * a20.x + o0.y * a20.y + o0.z * a20.z + o0.w * a20.w +
                o1.x * a21.x + o1.y * a21.y + o1.z * a21.z + o1.w * a21.w;
        if (gr < NN) {
            uint4 pk;
            pk.x = ((u32)f2bf(o0.y) << 16) | f2bf(o0.x);
            pk.y = ((u32)f2bf(o0.w) << 16) | f2bf(o0.z);
            pk.z = ((u32)f2bf(o1.y) << 16) | f2bf(o1.x);
            pk.w = ((u32)f2bf(o1.w) << 16) | f2bf(o1.z);
            // row = 128 bf16 = 64 u32; thread covers u32 [tcol*4, tcol*4+4)
            *reinterpret_cast<uint4*>(&zbf[gr * 64 + tcol * 4]) = pk;
        }
    }
    // reduce p1/p2 across the 16 tcol lanes (same trow group)
    #pragma unroll
    for (int d = 8; d; d >>= 1) {
        #pragma unroll
        for (int i = 0; i < 4; ++i) {
            p1[i] += __shfl_down(p1[i], d, 16);
            p2[i] += __shfl_down(p2[i], d, 16);
        }
    }
    if (tcol == 0) {
        #pragma unroll
        for (int i = 0; i < 4; ++i) {
            int gr = row0 + trow * 4 + i;
            if (gr < NN) { s1[gr] = p1[i]; s2[gr] = p2[i]; }
        }
    }
}

// --- aggregate (round-7 v2): lane-parallel h, broadcast FMA, register pool ---
__global__ __launch_bounds__(256) void k_aggregate(const u32* __restrict__ zbf,
                                                   const float* __restrict__ s1,
                                                   const float* __restrict__ s2,
                                                   const int* __restrict__ off,
                                                   const int* __restrict__ dst_s,
                                                   const int* __restrict__ idx,
                                                   float* __restrict__ pooled) {
    int wave = (blockIdx.x * 256 + threadIdx.x) >> 6;
    int lane = threadIdx.x & 63;
    int n0 = wave * KNODE;
    if (n0 >= NN) return;
    int n1 = n0 + KNODE;
    if (n1 > NN) n1 = NN;

    float pool0 = 0.f, pool1 = 0.f;
    int curg = idx[n0];

    for (int node = n0; node < n1; ++node) {
        int g = idx[node];
        if (g != curg) {
            atomicAdd(&pooled[curg * HH + lane * 2], pool0);
            atomicAdd(&pooled[curg * HH + lane * 2 + 1], pool1);
            pool0 = 0.f; pool1 = 0.f;
            curg = g;
        }
        int j0 = off[node], j1 = off[node + 1];
        float s1n = s1[node];
        float acc0 = 0.f, acc1 = 0.f, hsl = 0.f;

        for (int b = j0; b < j1; b += 64) {
            int cnt = j1 - b;
            if (cnt > 64) cnt = 64;
            // lane-parallel: lane l owns edge b+l
            int jj = b + ((lane < cnt) ? lane : 0);
            int dl = dst_s[jj];
            float ev = s1n + s2[dl];
            ev = (ev >= 0.f) ? ev : LRELU_A * ev;
            float hl = __expf(ev);
            if (lane >= cnt) hl = 0.f;
            hsl += hl;
            // broadcast loop: gather rows, FMA (uniform k -> v_readlane)
            int k = 0;
            for (; k + 4 <= cnt; k += 4) {
                int d0 = __shfl(dl, k),     d1 = __shfl(dl, k + 1);
                int d2 = __shfl(dl, k + 2), d3 = __shfl(dl, k + 3);
                float h0 = __shfl(hl, k),     h1 = __shfl(hl, k + 1);
                float h2 = __shfl(hl, k + 2), h3 = __shfl(hl, k + 3);
                u32 u0 = zbf[(d0 << 6) | lane];
                u32 u1 = zbf[(d1 << 6) | lane];
                u32 u2 = zbf[(d2 << 6) | lane];
                u32 u3 = zbf[(d3 << 6) | lane];
                acc0 += h0 * __uint_as_float(u0 << 16) +
                        h1 * __uint_as_float(u1 << 16) +
                        h2 * __uint_as_float(u2 << 16) +
                        h3 * __uint_as_float(u3 << 16);
                acc1 += h0 * __uint_as_float(u0 & 0xFFFF0000u) +
                        h1 * __uint_as_float(u1 & 0xFFFF0000u) +
                        h2 * __uint_as_float(u2 & 0xFFFF0000u) +
                        h3 * __uint_as_float(u3 & 0xFFFF0000u);
            }
            for (; k < cnt; ++k) {
                int dk = __shfl(dl, k);
                float hk = __shfl(hl, k);
                u32 u = zbf[(dk << 6) | lane];
                acc0 += hk * __uint_as_float(u << 16);
                acc1 += hk * __uint_as_float(u & 0xFFFF0000u);
            }
        }
        // wave-reduce the softmax denominator
        float hs = hsl;
        #pragma unroll
        for (int d = 32; d; d >>= 1) hs += __shfl_xor(hs, d);
        float inv = (hs > 0.f) ? 1.f / hs : 0.f;
        pool0 += fmaxf(acc0 * inv, 0.f);
        pool1 += fmaxf(acc1 * inv, 0.f);
    }
    atomicAdd(&pooled[curg * HH + lane * 2], pool0);
    atomicAdd(&pooled[curg * HH + lane * 2 + 1], pool1);
}

// ---------------- batchnorm stats -> scale/shift ----------------
__global__ __launch_bounds__(512) void k_bn(const float* __restrict__ pooled,
                                            const float* __restrict__ gamma,
                                            const float* __restrict__ beta,
                                            float* __restrict__ scale,
                                            float* __restrict__ shift) {
    __shared__ float sm[512], sm2[512];
    int f = threadIdx.x & 127, q = threadIdx.x >> 7;
    float s = 0.f, ss = 0.f;
    for (int g = q; g < GG; g += 4) {
        float v = pooled[g * HH + f];
        s += v;
        ss += v * v;
    }
    sm[threadIdx.x] = s;
    sm2[threadIdx.x] = ss;
    __syncthreads();
    if (q == 0) {
        s  = sm[f] + sm[f + 128] + sm[f + 256] + sm[f + 384];
        ss = sm2[f] + sm2[f + 128] + sm2[f + 256] + sm2[f + 384];
        float mean = s / GG;
        float var  = ss / GG - mean * mean;  // biased (jnp.var default)
        float sc = gamma[f] * rsqrtf(var + BN_EPS);
        scale[f] = sc;
        shift[f] = beta[f] - mean * sc;
    }
}

// ---------------- head: BN affine -> fc1+relu -> fc2 -> log_softmax --------
__global__ __launch_bounds__(128) void k_head(const float* __restrict__ pooled,
                                              const float* __restrict__ scale,
                                              const float* __restrict__ shift,
                                              const float* __restrict__ fc1w,
                                              const float* __restrict__ fc1b,
                                              const float* __restrict__ fc2w,
                                              const float* __restrict__ fc2b,
                                              float* __restrict__ out) {
    __shared__ __align__(16) float xb[128];
    __shared__ __align__(16) float h1[128];
    __shared__ float lg[16];
    int g = blockIdx.x;
    int t = threadIdx.x;
    xb[t] = pooled[g * HH + t] * scale[t] + shift[t];
    __syncthreads();
    float acc = 0.f;
    const float4* wr = reinterpret_cast<const float4*>(&fc1w[t * HH]);
    #pragma unroll 8
    for (int k = 0; k < 32; ++k) {
        float4 w4 = wr[k];
        float4 xv = *reinterpret_cast<const float4*>(&xb[k * 4]);
        acc += w4.x * xv.x + w4.y * xv.y + w4.z * xv.z + w4.w * xv.w;
    }
    acc += fc1b[t];
    h1[t] = (acc > 0.f) ? acc : 0.f;
    __syncthreads();
    if (t < CC) {
        float a = 0.f;
        const float4* w2 = reinterpret_cast<const float4*>(&fc2w[t * HH]);
        #pragma unroll 8
        for (int k = 0; k < 32; ++k) {
            float4 w4 = w2[k];
            float4 hv = *reinterpret_cast<const float4*>(&h1[k * 4]);
            a += w4.x * hv.x + w4.y * hv.y + w4.z * hv.z + w4.w * hv.w;
        }
        lg[t] = a + fc2b[t];
    }
    __syncthreads();
    if (t == 0) {
        float mx = lg[0];
        for (int c = 1; c < CC; ++c) mx = fmaxf(mx, lg[c]);
        float se = 0.f;
        for (int c = 0; c < CC; ++c) se += __expf(lg[c] - mx);
        float lse = mx + logf(se);
        for (int c = 0; c < CC; ++c) out[g * CC + c] = lg[c] - lse;
    }
}

// ---------------- launch ----------------
extern "C" void kernel_launch(void* const* d_in, const int* in_sizes, int n_in,
                              void* d_out, int out_size, void* d_ws, size_t ws_size,
                              hipStream_t stream) {
    const float* x_in  = (const float*)d_in[0];
    const int*   eidx  = (const int*)d_in[1];
    const int*   src   = eidx;
    const int*   dst   = eidx + NE;
    const int*   idx   = (const int*)d_in[2];
    const float* fc_w  = (const float*)d_in[3];
    const float* a1    = (const float*)d_in[4];
    const float* a2    = (const float*)d_in[5];
    const float* fc1w  = (const float*)d_in[6];
    const float* fc1b  = (const float*)d_in[7];
    const float* fc2w  = (const float*)d_in[8];
    const float* fc2b  = (const float*)d_in[9];
    const float* gamma = (const float*)d_in[10];
    const float* beta  = (const float*)d_in[11];
    float* out = (float*)d_out;

    char* p = (char*)d_ws;
    auto alloc = [&](size_t bytes) {
        char* r = p;
        p += (bytes + 255) & ~(size_t)255;
        return r;
    };
    double* st     = (double*)alloc(4 * sizeof(double));
    float*  wsum   = (float*)alloc(HH * sizeof(float));
    float*  musig  = (float*)alloc(4 * sizeof(float));
    float*  scale  = (float*)alloc(HH * sizeof(float));
    float*  shift  = (float*)alloc(HH * sizeof(float));
    float*  wt     = (float*)alloc((size_t)DD * HH * sizeof(float));
    u8*     cnt_t  = (u8*)alloc((size_t)TT * NN * sizeof(u8));
    u8*     rel    = (u8*)alloc((size_t)TT * NN * sizeof(u8));
    u8*     lrank  = (u8*)alloc((size_t)NE * sizeof(u8));
    int*    part   = (int*)alloc(SB * sizeof(int));
    int*    off    = (int*)alloc((NN + 1) * sizeof(int));
    int*    dst_s  = (int*)alloc((size_t)NE * sizeof(int));
    u32*    zbf    = (u32*)alloc((size_t)NN * (HH / 2) * sizeof(u32));
    float*  s1     = (float*)alloc(NN * sizeof(float));
    float*  s2     = (float*)alloc(NN * sizeof(float));
    float*  pooled = (float*)alloc((size_t)GG * HH * sizeof(float));

    hipMemsetAsync(st, 0, 4 * sizeof(double), stream);
    hipMemsetAsync(pooled, 0, (size_t)GG * HH * sizeof(float), stream);

    k_stats<<<1024, 256, 0, stream>>>(x_in, st);
    k_finalize<<<1, 128, 0, stream>>>(fc_w, st, wsum, musig);
    k_wt<<<(DD * HH) / 256, 256, 0, stream>>>(fc_w, wt);
    k_thist<<<TT, 256, 0, stream>>>(src, cnt_t, lrank);
    k_rel<<<SB, 256, 0, stream>>>(cnt_t, rel, off, part);
    k_scan2<<<1, 256, 0, stream>>>(part);
    k_add<<<SB, 256, 0, stream>>>(off, part);
    k_gemm<<<(NN + 63) / 64, 256, 0, stream>>>(x_in, wt, wsum, musig, a1, a2,
                                               zbf, s1, s2);
    k_scatter3<<<2048, 256, 0, stream>>>(src, dst, off, rel, lrank, dst_s);
    int nwaves = (NN + KNODE - 1) / KNODE;          // 6250
    int nblocks = (nwaves + 3) / 4;                 // 4 waves per 256-thr block
    k_aggregate<<<nblocks, 256, 0, stream>>>(zbf, s1, s2, off, dst_s, idx, pooled);
    k_bn<<<1, 512, 0, stream>>>(pooled, gamma, beta, scale, shift);
    k_head<<<GG, 128, 0, stream>>>(pooled, scale, shift, fc1w, fc1b, fc2w, fc2b, out);
}

// Round 10
// 240.905 us; speedup vs baseline: 1.0883x; 1.0410x over previous
//
#include <hip/hip_runtime.h>

#define NN 50000
#define NE 1600000
#define DD 128
#define HH 128
#define CC 10
#define GG 512
#define LRELU_A 0.05f
#define BN_EPS 1e-5f

#define TT 256          // edge tiles
#define EPT (NE / TT)   // 6250 edges per tile
#define NB 196          // src buckets (256 consecutive nodes each)
#define NPB 256         // nodes per bucket
#define KNODE 8         // nodes per wave in aggregate

typedef unsigned int u32;
typedef unsigned short u16;
typedef unsigned char u8;

__device__ __forceinline__ u16 f2bf(float f) {
    u32 u = __float_as_uint(f);
    u32 r = u + 0x7FFFu + ((u >> 16) & 1u);
    return (u16)(r >> 16);
}

// ---------------- stats: global sum & sumsq of x_in ----------------
__global__ __launch_bounds__(256) void k_stats(const float* __restrict__ x,
                                               double* __restrict__ st) {
    const int M4 = NN * DD / 4;
    double s = 0.0, ss = 0.0;
    for (int i = blockIdx.x * blockDim.x + threadIdx.x; i < M4;
         i += gridDim.x * blockDim.x) {
        float4 v = reinterpret_cast<const float4*>(x)[i];
        s  += (double)v.x + (double)v.y + (double)v.z + (double)v.w;
        ss += (double)v.x * v.x + (double)v.y * v.y + (double)v.z * v.z +
              (double)v.w * v.w;
    }
    for (int d = 32; d; d >>= 1) { s += __shfl_down(s, d); ss += __shfl_down(ss, d); }
    __shared__ double ls[4], lss[4];
    int lane = threadIdx.x & 63, w = threadIdx.x >> 6;
    if (lane == 0) { ls[w] = s; lss[w] = ss; }
    __syncthreads();
    if (threadIdx.x == 0) {
        s  = ls[0] + ls[1] + ls[2] + ls[3];
        ss = lss[0] + lss[1] + lss[2] + lss[3];
        atomicAdd(&st[0], s);
        atomicAdd(&st[1], ss);
    }
}

// ---------------- finalize stats + per-output-row weight sums ----------------
__global__ __launch_bounds__(128) void k_finalize(const float* __restrict__ fc_w,
                                                  const double* __restrict__ st,
                                                  float* __restrict__ wsum,
                                                  float* __restrict__ musig) {
    int c = threadIdx.x;
    float s = 0.f;
    for (int k = 0; k < DD; ++k) s += fc_w[c * DD + k];
    wsum[c] = s;
    if (c == 0) {
        double M = (double)NN * DD;
        double mean = st[0] / M;
        double var  = (st[1] - st[0] * st[0] / M) / (M - 1.0);  // ddof=1
        musig[0] = (float)mean;
        musig[1] = (float)(1.0 / sqrt(var));
    }
}

// ---------------- transpose fc_w -> wt[k][c] (global, 64 KB) ----------------
__global__ __launch_bounds__(256) void k_wt(const float* __restrict__ w,
                                            float* __restrict__ wt) {
    int i = blockIdx.x * 256 + threadIdx.x;  // i = k*128 + c
    int k = i >> 7, c = i & 127;
    wt[i] = w[c * DD + k];
}

// ------ pass A: per-tile bucket histogram + per-edge rank (u8) ------
// bucket b = src >> 8 (196 buckets of 256 nodes). Count per (tile,bucket)
// ~= Binomial(6250, 1/196), mean 32 -> rank fits u8 with huge margin.
__global__ __launch_bounds__(256) void k_bcount(const int* __restrict__ src,
                                                u16* __restrict__ cnt_b,
                                                u8* __restrict__ rank_e) {
    __shared__ u32 h[NB];
    int t = blockIdx.x, tid = threadIdx.x;
    for (int i = tid; i < NB; i += 256) h[i] = 0;
    __syncthreads();
    int e0 = t * EPT;
    for (int i = tid; i < EPT; i += 256) {
        int b = src[e0 + i] >> 8;
        u32 old = atomicAdd(&h[b], 1u);
        rank_e[e0 + i] = (u8)old;
    }
    __syncthreads();
    for (int i = tid; i < NB; i += 256) cnt_b[t * NB + i] = (u16)h[i];
}

// ------ pass A': rel_b[t][b] = prefix over tiles; bucket bases ------
__global__ __launch_bounds__(256) void k_brel(const u16* __restrict__ cnt_b,
                                              u16* __restrict__ rel_b,
                                              int* __restrict__ base_b) {
    __shared__ int sm[256];
    int b = threadIdx.x;
    int run = 0;
    if (b < NB) {
        for (int t = 0; t < TT; ++t) {
            int c = cnt_b[t * NB + b];
            rel_b[t * NB + b] = (u16)run;
            run += c;
        }
    }
    sm[b] = (b < NB) ? run : 0;
    __syncthreads();
    int v = sm[b];
    for (int d = 1; d < 256; d <<= 1) {
        int x = 0;
        if (b >= d) x = sm[b - d];
        __syncthreads();
        if (b >= d) sm[b] += x;
        __syncthreads();
    }
    if (b < NB) base_b[b] = sm[b] - v;  // exclusive
    if (b == NB - 1) base_b[NB] = sm[b];  // = NE
}

// ------ pass B: scatter into bucket-sorted ebuf (semi-coalesced runs) ------
// packed: (dst << 8) | (src & 255)   [dst < 50000 fits 16 bits]
__global__ __launch_bounds__(256) void k_bscat(const int* __restrict__ src,
                                               const int* __restrict__ dst,
                                               const u16* __restrict__ rel_b,
                                               const u8* __restrict__ rank_e,
                                               const int* __restrict__ base_b,
                                               u32* __restrict__ ebuf) {
    int t = blockIdx.x, tid = threadIdx.x;
    int e0 = t * EPT;
    for (int i = tid; i < EPT; i += 256) {
        int s = src[e0 + i];
        int b = s >> 8;
        int pos = base_b[b] + (int)rel_b[t * NB + b] + (int)rank_e[e0 + i];
        ebuf[pos] = ((u32)dst[e0 + i] << 8) | (u32)(s & 255);
    }
}

// ------ pass C: per-bucket LDS counting sort -> off[] + dst_s ------
// One block per bucket; dst_s writes land in a 33 KB L1/L2-hot window.
__global__ __launch_bounds__(256) void k_bcsr(const u32* __restrict__ ebuf,
                                              const int* __restrict__ base_b,
                                              int* __restrict__ off,
                                              int* __restrict__ dst_s) {
    __shared__ u32 hist[NPB];
    __shared__ u32 cur[NPB];
    __shared__ int sm[256];
    int b = blockIdx.x, tid = threadIdx.x;
    int ebase = base_b[b], eend = base_b[b + 1];
    int m = eend - ebase;
    hist[tid] = 0;
    __syncthreads();
    for (int i = tid; i < m; i += 256)
        atomicAdd(&hist[ebuf[ebase + i] & 255u], 1u);
    __syncthreads();
    int v = (int)hist[tid];
    sm[tid] = v;
    __syncthreads();
    for (int d = 1; d < 256; d <<= 1) {
        int x = 0;
        if (tid >= d) x = sm[tid - d];
        __syncthreads();
        if (tid >= d) sm[tid] += x;
        __syncthreads();
    }
    int st = sm[tid] - v;  // exclusive prefix within bucket
    cur[tid] = (u32)st;
    int n = b * NPB + tid;
    if (n < NN) off[n] = ebase + st;
    if (b == NB - 1 && tid == 0) off[NN] = NE;
    __syncthreads();
    for (int i = tid; i < m; i += 256) {
        u32 e = ebuf[ebase + i];
        int ls = (int)(e & 255u);
        int p = (int)atomicAdd(&cur[ls], 1u);
        dst_s[ebase + p] = (int)(e >> 8);
    }
}

// ------ z = x_std @ fc_w^T, fused: z bf16, s1=z@a1, s2=z@a2 ------
#define PADX 132
__global__ __launch_bounds__(256, 4) void k_gemm(const float* __restrict__ x,
                                                 const float* __restrict__ wt,
                                                 const float* __restrict__ wsum,
                                                 const float* __restrict__ musig,
                                                 const float* __restrict__ a1,
                                                 const float* __restrict__ a2,
                                                 u32* __restrict__ zbf,
                                                 float* __restrict__ s1,
                                                 float* __restrict__ s2) {
    __shared__ float xs[64][PADX];  // ~34 KB -> 4 blocks/CU
    int tid = threadIdx.x;
    int row0 = blockIdx.x * 64;

    for (int i = tid; i < 64 * 32; i += 256) {
        int r = i >> 5;
        int m = i & 31;
        int gr = row0 + r;
        float4 v = (gr < NN) ? reinterpret_cast<const float4*>(x)[gr * 32 + m]
                             : make_float4(0.f, 0.f, 0.f, 0.f);
        *reinterpret_cast<float4*>(&xs[r][m << 2]) = v;
    }
    __syncthreads();

    int trow = tid >> 4, tcol = tid & 15;
    float acc[4][8];
    #pragma unroll
    for (int i = 0; i < 4; ++i)
        #pragma unroll
        for (int j = 0; j < 8; ++j) acc[i][j] = 0.f;

    const float4* wt4 = reinterpret_cast<const float4*>(wt);
    for (int k = 0; k < 128; k += 4) {
        float4 xv[4];
        #pragma unroll
        for (int i = 0; i < 4; ++i)
            xv[i] = *reinterpret_cast<const float4*>(&xs[trow * 4 + i][k]);
        #pragma unroll
        for (int kk = 0; kk < 4; ++kk) {
            float4 w0 = wt4[(k + kk) * 32 + tcol * 2];
            float4 w1 = wt4[(k + kk) * 32 + tcol * 2 + 1];
            #pragma unroll
            for (int i = 0; i < 4; ++i) {
                float a = (kk == 0) ? xv[i].x
                        : (kk == 1) ? xv[i].y
                        : (kk == 2) ? xv[i].z : xv[i].w;
                acc[i][0] += a * w0.x; acc[i][1] += a * w0.y;
                acc[i][2] += a * w0.z; acc[i][3] += a * w0.w;
                acc[i][4] += a * w1.x; acc[i][5] += a * w1.y;
                acc[i][6] += a * w1.z; acc[i][7] += a * w1.w;
            }
        }
    }

    float mu = musig[0], isig = musig[1];
    int c0 = tcol * 8;
    float4 a10 = *reinterpret_cast<const float4*>(&a1[c0]);
    float4 a11 = *reinterpret_cast<const float4*>(&a1[c0 + 4]);
    float4 a20 = *reinterpret_cast<const float4*>(&a2[c0]);
    float4 a21 = *reinterpret_cast<const float4*>(&a2[c0 + 4]);
    float ws0x = wsum[c0 + 0], ws0y = wsum[c0 + 1], ws0z = wsum[c0 + 2], ws0w = wsum[c0 + 3];
    float ws1x = wsum[c0 + 4], ws1y = wsum[c0 + 5], ws1z = wsum[c0 + 6], ws1w = wsum[c0 + 7];

    float p1[4], p2[4];
    #pragma unroll
    for (int i = 0; i < 4; ++i) {
        int gr = row0 + trow * 4 + i;
        float4 o0, o1;
        o0.x = (acc[i][0] - mu * ws0x) * isig;
        o0.y = (acc[i][1] - mu * ws0y) * isig;
        o0.z = (acc[i][2] - mu * ws0z) * isig;
        o0.w = (acc[i][3] - mu * ws0w) * isig;
        o1.x = (acc[i][4] - mu * ws1x) * isig;
        o1.y = (acc[i][5] - mu * ws1y) * isig;
        o1.z = (acc[i][6] - mu * ws1z) * isig;
        o1.w = (acc[i][7] - mu * ws1w) * isig;
        p1[i] = o0.x * a10.x + o0.y * a10.y + o0.z * a10.z + o0.w * a10.w +
                o1.x * a11.x + o1.y * a11.y + o1.z * a11.z + o1.w * a11.w;
        p2[i] = o0.x * a20.x + o0.y * a20.y + o0.z * a20.z + o0.w * a20.w +
                o1.x * a21.x + o1.y * a21.y + o1.z * a21.z + o1.w * a21.w;
        if (gr < NN) {
            uint4 pk;
            pk.x = ((u32)f2bf(o0.y) << 16) | f2bf(o0.x);
            pk.y = ((u32)f2bf(o0.w) << 16) | f2bf(o0.z);
            pk.z = ((u32)f2bf(o1.y) << 16) | f2bf(o1.x);
            pk.w = ((u32)f2bf(o1.w) << 16) | f2bf(o1.z);
            // row = 128 bf16 = 64 u32; thread covers u32 [tcol*4, tcol*4+4)
            *reinterpret_cast<uint4*>(&zbf[gr * 64 + tcol * 4]) = pk;
        }
    }
    // reduce p1/p2 across the 16 tcol lanes (same trow group)
    #pragma unroll
    for (int d = 8; d; d >>= 1) {
        #pragma unroll
        for (int i = 0; i < 4; ++i) {
            p1[i] += __shfl_down(p1[i], d, 16);
            p2[i] += __shfl_down(p2[i], d, 16);
        }
    }
    if (tcol == 0) {
        #pragma unroll
        for (int i = 0; i < 4; ++i) {
            int gr = row0 + trow * 4 + i;
            if (gr < NN) { s1[gr] = p1[i]; s2[gr] = p2[i]; }
        }
    }
}

// --- aggregate: lane-parallel h, broadcast FMA, register pool (r7 version) ---
__global__ __launch_bounds__(256) void k_aggregate(const u32* __restrict__ zbf,
                                                   const float* __restrict__ s1,
                                                   const float* __restrict__ s2,
                                                   const int* __restrict__ off,
                                                   const int* __restrict__ dst_s,
                                                   const int* __restrict__ idx,
                                                   float* __restrict__ pooled) {
    int wave = (blockIdx.x * 256 + threadIdx.x) >> 6;
    int lane = threadIdx.x & 63;
    int n0 = wave * KNODE;
    if (n0 >= NN) return;
    int n1 = n0 + KNODE;
    if (n1 > NN) n1 = NN;

    float pool0 = 0.f, pool1 = 0.f;
    int curg = idx[n0];

    for (int node = n0; node < n1; ++node) {
        int g = idx[node];
        if (g != curg) {
            atomicAdd(&pooled[curg * HH + lane * 2], pool0);
            atomicAdd(&pooled[curg * HH + lane * 2 + 1], pool1);
            pool0 = 0.f; pool1 = 0.f;
            curg = g;
        }
        int j0 = off[node], j1 = off[node + 1];
        float s1n = s1[node];
        float acc0 = 0.f, acc1 = 0.f, hsl = 0.f;

        for (int b = j0; b < j1; b += 64) {
            int cnt = j1 - b;
            if (cnt > 64) cnt = 64;
            // lane-parallel: lane l owns edge b+l
            int jj = b + ((lane < cnt) ? lane : 0);
            int dl = dst_s[jj];
            float ev = s1n + s2[dl];
            ev = (ev >= 0.f) ? ev : LRELU_A * ev;
            float hl = __expf(ev);
            if (lane >= cnt) hl = 0.f;
            hsl += hl;
            // broadcast loop: gather rows, FMA (uniform k -> v_readlane)
            int k = 0;
            for (; k + 4 <= cnt; k += 4) {
                int d0 = __shfl(dl, k),     d1 = __shfl(dl, k + 1);
                int d2 = __shfl(dl, k + 2), d3 = __shfl(dl, k + 3);
                float h0 = __shfl(hl, k),     h1 = __shfl(hl, k + 1);
                float h2 = __shfl(hl, k + 2), h3 = __shfl(hl, k + 3);
                u32 u0 = zbf[(d0 << 6) | lane];
                u32 u1 = zbf[(d1 << 6) | lane];
                u32 u2 = zbf[(d2 << 6) | lane];
                u32 u3 = zbf[(d3 << 6) | lane];
                acc0 += h0 * __uint_as_float(u0 << 16) +
                        h1 * __uint_as_float(u1 << 16) +
                        h2 * __uint_as_float(u2 << 16) +
                        h3 * __uint_as_float(u3 << 16);
                acc1 += h0 * __uint_as_float(u0 & 0xFFFF0000u) +
                        h1 * __uint_as_float(u1 & 0xFFFF0000u) +
                        h2 * __uint_as_float(u2 & 0xFFFF0000u) +
                        h3 * __uint_as_float(u3 & 0xFFFF0000u);
            }
            for (; k < cnt; ++k) {
                int dk = __shfl(dl, k);
                float hk = __shfl(hl, k);
                u32 u = zbf[(dk << 6) | lane];
                acc0 += hk * __uint_as_float(u << 16);
                acc1 += hk * __uint_as_float(u & 0xFFFF0000u);
            }
        }
        // wave-reduce the softmax denominator
        float hs = hsl;
        #pragma unroll
        for (int d = 32; d; d >>= 1) hs += __shfl_xor(hs, d);
        float inv = (hs > 0.f) ? 1.f / hs : 0.f;
        pool0 += fmaxf(acc0 * inv, 0.f);
        pool1 += fmaxf(acc1 * inv, 0.f);
    }
    atomicAdd(&pooled[curg * HH + lane * 2], pool0);
    atomicAdd(&pooled[curg * HH + lane * 2 + 1], pool1);
}

// ---------------- batchnorm stats -> scale/shift ----------------
__global__ __launch_bounds__(512) void k_bn(const float* __restrict__ pooled,
                                            const float* __restrict__ gamma,
                                            const float* __restrict__ beta,
                                            float* __restrict__ scale,
                                            float* __restrict__ shift) {
    __shared__ float sm[512], sm2[512];
    int f = threadIdx.x & 127, q = threadIdx.x >> 7;
    float s = 0.f, ss = 0.f;
    for (int g = q; g < GG; g += 4) {
        float v = pooled[g * HH + f];
        s += v;
        ss += v * v;
    }
    sm[threadIdx.x] = s;
    sm2[threadIdx.x] = ss;
    __syncthreads();
    if (q == 0) {
        s  = sm[f] + sm[f + 128] + sm[f + 256] + sm[f + 384];
        ss = sm2[f] + sm2[f + 128] + sm2[f + 256] + sm2[f + 384];
        float mean = s / GG;
        float var  = ss / GG - mean * mean;  // biased (jnp.var default)
        float sc = gamma[f] * rsqrtf(var + BN_EPS);
        scale[f] = sc;
        shift[f] = beta[f] - mean * sc;
    }
}

// ---------------- head: BN affine -> fc1+relu -> fc2 -> log_softmax --------
__global__ __launch_bounds__(128) void k_head(const float* __restrict__ pooled,
                                              const float* __restrict__ scale,
                                              const float* __restrict__ shift,
                                              const float* __restrict__ fc1w,
                                              const float* __restrict__ fc1b,
                                              const float* __restrict__ fc2w,
                                              const float* __restrict__ fc2b,
                                              float* __restrict__ out) {
    __shared__ __align__(16) float xb[128];
    __shared__ __align__(16) float h1[128];
    __shared__ float lg[16];
    int g = blockIdx.x;
    int t = threadIdx.x;
    xb[t] = pooled[g * HH + t] * scale[t] + shift[t];
    __syncthreads();
    float acc = 0.f;
    const float4* wr = reinterpret_cast<const float4*>(&fc1w[t * HH]);
    #pragma unroll 8
    for (int k = 0; k < 32; ++k) {
        float4 w4 = wr[k];
        float4 xv = *reinterpret_cast<const float4*>(&xb[k * 4]);
        acc += w4.x * xv.x + w4.y * xv.y + w4.z * xv.z + w4.w * xv.w;
    }
    acc += fc1b[t];
    h1[t] = (acc > 0.f) ? acc : 0.f;
    __syncthreads();
    if (t < CC) {
        float a = 0.f;
        const float4* w2 = reinterpret_cast<const float4*>(&fc2w[t * HH]);
        #pragma unroll 8
        for (int k = 0; k < 32; ++k) {
            float4 w4 = w2[k];
            float4 hv = *reinterpret_cast<const float4*>(&h1[k * 4]);
            a += w4.x * hv.x + w4.y * hv.y + w4.z * hv.z + w4.w * hv.w;
        }
        lg[t] = a + fc2b[t];
    }
    __syncthreads();
    if (t == 0) {
        float mx = lg[0];
        for (int c = 1; c < CC; ++c) mx = fmaxf(mx, lg[c]);
        float se = 0.f;
        for (int c = 0; c < CC; ++c) se += __expf(lg[c] - mx);
        float lse = mx + logf(se);
        for (int c = 0; c < CC; ++c) out[g * CC + c] = lg[c] - lse;
    }
}

// ---------------- launch ----------------
extern "C" void kernel_launch(void* const* d_in, const int* in_sizes, int n_in,
                              void* d_out, int out_size, void* d_ws, size_t ws_size,
                              hipStream_t stream) {
    const float* x_in  = (const float*)d_in[0];
    const int*   eidx  = (const int*)d_in[1];
    const int*   src   = eidx;
    const int*   dst   = eidx + NE;
    const int*   idx   = (const int*)d_in[2];
    const float* fc_w  = (const float*)d_in[3];
    const float* a1    = (const float*)d_in[4];
    const float* a2    = (const float*)d_in[5];
    const float* fc1w  = (const float*)d_in[6];
    const float* fc1b  = (const float*)d_in[7];
    const float* fc2w  = (const float*)d_in[8];
    const float* fc2b  = (const float*)d_in[9];
    const float* gamma = (const float*)d_in[10];
    const float* beta  = (const float*)d_in[11];
    float* out = (float*)d_out;

    char* p = (char*)d_ws;
    auto alloc = [&](size_t bytes) {
        char* r = p;
        p += (bytes + 255) & ~(size_t)255;
        return r;
    };
    double* st     = (double*)alloc(4 * sizeof(double));
    float*  wsum   = (float*)alloc(HH * sizeof(float));
    float*  musig  = (float*)alloc(4 * sizeof(float));
    float*  scale  = (float*)alloc(HH * sizeof(float));
    float*  shift  = (float*)alloc(HH * sizeof(float));
    float*  wt     = (float*)alloc((size_t)DD * HH * sizeof(float));
    u16*    cnt_b  = (u16*)alloc((size_t)TT * NB * sizeof(u16));
    u16*    rel_b  = (u16*)alloc((size_t)TT * NB * sizeof(u16));
    u8*     rank_e = (u8*)alloc((size_t)NE * sizeof(u8));
    int*    base_b = (int*)alloc((NB + 1) * sizeof(int));
    u32*    ebuf   = (u32*)alloc((size_t)NE * sizeof(u32));
    int*    off    = (int*)alloc((NN + 1) * sizeof(int));
    int*    dst_s  = (int*)alloc((size_t)NE * sizeof(int));
    u32*    zbf    = (u32*)alloc((size_t)NN * (HH / 2) * sizeof(u32));
    float*  s1     = (float*)alloc(NN * sizeof(float));
    float*  s2     = (float*)alloc(NN * sizeof(float));
    float*  pooled = (float*)alloc((size_t)GG * HH * sizeof(float));

    hipMemsetAsync(st, 0, 4 * sizeof(double), stream);
    hipMemsetAsync(pooled, 0, (size_t)GG * HH * sizeof(float), stream);

    k_stats<<<1024, 256, 0, stream>>>(x_in, st);
    k_finalize<<<1, 128, 0, stream>>>(fc_w, st, wsum, musig);
    k_wt<<<(DD * HH) / 256, 256, 0, stream>>>(fc_w, wt);
    k_bcount<<<TT, 256, 0, stream>>>(src, cnt_b, rank_e);
    k_brel<<<1, 256, 0, stream>>>(cnt_b, rel_b, base_b);
    k_gemm<<<(NN + 63) / 64, 256, 0, stream>>>(x_in, wt, wsum, musig, a1, a2,
                                               zbf, s1, s2);
    k_bscat<<<TT, 256, 0, stream>>>(src, dst, rel_b, rank_e, base_b, ebuf);
    k_bcsr<<<NB, 256, 0, stream>>>(ebuf, base_b, off, dst_s);
    int nwaves = (NN + KNODE - 1) / KNODE;          // 6250
    int nblocks = (nwaves + 3) / 4;                 // 4 waves per 256-thr block
    k_aggregate<<<nblocks, 256, 0, stream>>>(zbf, s1, s2, off, dst_s, idx, pooled);
    k_bn<<<1, 512, 0, stream>>>(pooled, gamma, beta, scale, shift);
    k_head<<<GG, 128, 0, stream>>>(pooled, scale, shift, fc1w, fc1b, fc2w, fc2b, out);
}

// Round 11
// 238.666 us; speedup vs baseline: 1.0985x; 1.0094x over previous
//
#include <hip/hip_runtime.h>

#define NN 50000
#define NE 1600000
#define DD 128
#define HH 128
#define CC 10
#define GG 512
#define LRELU_A 0.05f
#define BN_EPS 1e-5f

#define TT 256          // edge tiles
#define EPT (NE / TT)   // 6250 edges per tile
#define NB 196          // src buckets (256 consecutive nodes each)
#define NPB 256         // nodes per bucket
#define KNODE 8         // nodes per wave in aggregate

typedef unsigned int u32;
typedef unsigned short u16;
typedef unsigned char u8;

__device__ __forceinline__ u16 f2bf(float f) {
    u32 u = __float_as_uint(f);
    u32 r = u + 0x7FFFu + ((u >> 16) & 1u);
    return (u16)(r >> 16);
}

// ---------------- stats: global sum & sumsq of x_in ----------------
__global__ __launch_bounds__(256) void k_stats(const float* __restrict__ x,
                                               double* __restrict__ st) {
    const int M4 = NN * DD / 4;
    double s = 0.0, ss = 0.0;
    for (int i = blockIdx.x * blockDim.x + threadIdx.x; i < M4;
         i += gridDim.x * blockDim.x) {
        float4 v = reinterpret_cast<const float4*>(x)[i];
        s  += (double)v.x + (double)v.y + (double)v.z + (double)v.w;
        ss += (double)v.x * v.x + (double)v.y * v.y + (double)v.z * v.z +
              (double)v.w * v.w;
    }
    for (int d = 32; d; d >>= 1) { s += __shfl_down(s, d); ss += __shfl_down(ss, d); }
    __shared__ double ls[4], lss[4];
    int lane = threadIdx.x & 63, w = threadIdx.x >> 6;
    if (lane == 0) { ls[w] = s; lss[w] = ss; }
    __syncthreads();
    if (threadIdx.x == 0) {
        s  = ls[0] + ls[1] + ls[2] + ls[3];
        ss = lss[0] + lss[1] + lss[2] + lss[3];
        atomicAdd(&st[0], s);
        atomicAdd(&st[1], ss);
    }
}

// ------ fused: wsum + musig + wt transpose (one block, 256 threads) ------
__global__ __launch_bounds__(256) void k_prep(const float* __restrict__ fc_w,
                                              const double* __restrict__ st,
                                              float* __restrict__ wsum,
                                              float* __restrict__ musig,
                                              float* __restrict__ wt) {
    int t = threadIdx.x;
    if (t < 128) {
        float s = 0.f;
        for (int k = 0; k < DD; ++k) s += fc_w[t * DD + k];
        wsum[t] = s;
    }
    if (t == 0) {
        double M = (double)NN * DD;
        double mean = st[0] / M;
        double var  = (st[1] - st[0] * st[0] / M) / (M - 1.0);  // ddof=1
        musig[0] = (float)mean;
        musig[1] = (float)(1.0 / sqrt(var));
    }
    for (int i = t; i < DD * HH; i += 256) {
        int k = i >> 7, c = i & 127;
        wt[i] = fc_w[c * DD + k];
    }
}

// ------ pass A: per-tile bucket histogram + per-edge rank (u8) ------
__global__ __launch_bounds__(256) void k_bcount(const int* __restrict__ src,
                                                u16* __restrict__ cnt_b,
                                                u8* __restrict__ rank_e) {
    __shared__ u32 h[NB];
    int t = blockIdx.x, tid = threadIdx.x;
    for (int i = tid; i < NB; i += 256) h[i] = 0;
    __syncthreads();
    int e0 = t * EPT;
    for (int i = tid; i < EPT; i += 256) {
        int b = src[e0 + i] >> 8;
        u32 old = atomicAdd(&h[b], 1u);
        rank_e[e0 + i] = (u8)old;
    }
    __syncthreads();
    for (int i = tid; i < NB; i += 256) cnt_b[t * NB + i] = (u16)h[i];
}

// ------ pass A': rel_b[t][b] = prefix over tiles; bucket bases ------
__global__ __launch_bounds__(256) void k_brel(const u16* __restrict__ cnt_b,
                                              u16* __restrict__ rel_b,
                                              int* __restrict__ base_b) {
    __shared__ int sm[256];
    int b = threadIdx.x;
    int run = 0;
    if (b < NB) {
        for (int t = 0; t < TT; ++t) {
            int c = cnt_b[t * NB + b];
            rel_b[t * NB + b] = (u16)run;
            run += c;
        }
    }
    sm[b] = (b < NB) ? run : 0;
    __syncthreads();
    int v = sm[b];
    for (int d = 1; d < 256; d <<= 1) {
        int x = 0;
        if (b >= d) x = sm[b - d];
        __syncthreads();
        if (b >= d) sm[b] += x;
        __syncthreads();
    }
    if (b < NB) base_b[b] = sm[b] - v;  // exclusive
    if (b == NB - 1) base_b[NB] = sm[b];  // = NE
}

// ------ pass B: scatter into bucket-sorted ebuf (semi-coalesced runs) ------
__global__ __launch_bounds__(256) void k_bscat(const int* __restrict__ src,
                                               const int* __restrict__ dst,
                                               const u16* __restrict__ rel_b,
                                               const u8* __restrict__ rank_e,
                                               const int* __restrict__ base_b,
                                               u32* __restrict__ ebuf) {
    int t = blockIdx.x, tid = threadIdx.x;
    int e0 = t * EPT;
    for (int i = tid; i < EPT; i += 256) {
        int s = src[e0 + i];
        int b = s >> 8;
        int pos = base_b[b] + (int)rel_b[t * NB + b] + (int)rank_e[e0 + i];
        ebuf[pos] = ((u32)dst[e0 + i] << 8) | (u32)(s & 255);
    }
}

// ------ pass C: per-bucket LDS counting sort -> off[] + dst_s ------
__global__ __launch_bounds__(256) void k_bcsr(const u32* __restrict__ ebuf,
                                              const int* __restrict__ base_b,
                                              int* __restrict__ off,
                                              int* __restrict__ dst_s) {
    __shared__ u32 hist[NPB];
    __shared__ u32 cur[NPB];
    __shared__ int sm[256];
    int b = blockIdx.x, tid = threadIdx.x;
    int ebase = base_b[b], eend = base_b[b + 1];
    int m = eend - ebase;
    hist[tid] = 0;
    __syncthreads();
    for (int i = tid; i < m; i += 256)
        atomicAdd(&hist[ebuf[ebase + i] & 255u], 1u);
    __syncthreads();
    int v = (int)hist[tid];
    sm[tid] = v;
    __syncthreads();
    for (int d = 1; d < 256; d <<= 1) {
        int x = 0;
        if (tid >= d) x = sm[tid - d];
        __syncthreads();
        if (tid >= d) sm[tid] += x;
        __syncthreads();
    }
    int st = sm[tid] - v;  // exclusive prefix within bucket
    cur[tid] = (u32)st;
    int n = b * NPB + tid;
    if (n < NN) off[n] = ebase + st;
    if (b == NB - 1 && tid == 0) off[NN] = NE;
    __syncthreads();
    for (int i = tid; i < m; i += 256) {
        u32 e = ebuf[ebase + i];
        int ls = (int)(e & 255u);
        int p = (int)atomicAdd(&cur[ls], 1u);
        dst_s[ebase + p] = (int)(e >> 8);
    }
}

// ------ z = x_std @ fc_w^T, fused: zbf, s1, s2. 128-row tile, 8 rows/thread --
#define PADX 132
__global__ __launch_bounds__(256, 2) void k_gemm(const float* __restrict__ x,
                                                 const float* __restrict__ wt,
                                                 const float* __restrict__ wsum,
                                                 const float* __restrict__ musig,
                                                 const float* __restrict__ a1,
                                                 const float* __restrict__ a2,
                                                 u32* __restrict__ zbf,
                                                 float* __restrict__ s1,
                                                 float* __restrict__ s2) {
    __shared__ float xs[128][PADX];  // ~67.6 KB -> 2 blocks/CU
    int tid = threadIdx.x;
    int row0 = blockIdx.x * 128;

    for (int i = tid; i < 128 * 32; i += 256) {
        int r = i >> 5;
        int m = i & 31;
        int gr = row0 + r;
        float4 v = (gr < NN) ? reinterpret_cast<const float4*>(x)[gr * 32 + m]
                             : make_float4(0.f, 0.f, 0.f, 0.f);
        *reinterpret_cast<float4*>(&xs[r][m << 2]) = v;
    }
    __syncthreads();

    int trow = tid >> 4, tcol = tid & 15;  // 16 row-groups x 8 rows
    float acc[8][8];
    #pragma unroll
    for (int i = 0; i < 8; ++i)
        #pragma unroll
        for (int j = 0; j < 8; ++j) acc[i][j] = 0.f;

    const float4* wt4 = reinterpret_cast<const float4*>(wt);
    for (int k = 0; k < 128; k += 4) {
        float4 xv[8];
        #pragma unroll
        for (int i = 0; i < 8; ++i)
            xv[i] = *reinterpret_cast<const float4*>(&xs[trow * 8 + i][k]);
        #pragma unroll
        for (int kk = 0; kk < 4; ++kk) {
            float4 w0 = wt4[(k + kk) * 32 + tcol * 2];
            float4 w1 = wt4[(k + kk) * 32 + tcol * 2 + 1];
            #pragma unroll
            for (int i = 0; i < 8; ++i) {
                float a = (kk == 0) ? xv[i].x
                        : (kk == 1) ? xv[i].y
                        : (kk == 2) ? xv[i].z : xv[i].w;
                acc[i][0] += a * w0.x; acc[i][1] += a * w0.y;
                acc[i][2] += a * w0.z; acc[i][3] += a * w0.w;
                acc[i][4] += a * w1.x; acc[i][5] += a * w1.y;
                acc[i][6] += a * w1.z; acc[i][7] += a * w1.w;
            }
        }
    }

    float mu = musig[0], isig = musig[1];
    int c0 = tcol * 8;
    float4 a10 = *reinterpret_cast<const float4*>(&a1[c0]);
    float4 a11 = *reinterpret_cast<const float4*>(&a1[c0 + 4]);
    float4 a20 = *reinterpret_cast<const float4*>(&a2[c0]);
    float4 a21 = *reinterpret_cast<const float4*>(&a2[c0 + 4]);
    float ws0x = wsum[c0 + 0], ws0y = wsum[c0 + 1], ws0z = wsum[c0 + 2], ws0w = wsum[c0 + 3];
    float ws1x = wsum[c0 + 4], ws1y = wsum[c0 + 5], ws1z = wsum[c0 + 6], ws1w = wsum[c0 + 7];

    float p1[8], p2[8];
    #pragma unroll
    for (int i = 0; i < 8; ++i) {
        int gr = row0 + trow * 8 + i;
        float4 o0, o1;
        o0.x = (acc[i][0] - mu * ws0x) * isig;
        o0.y = (acc[i][1] - mu * ws0y) * isig;
        o0.z = (acc[i][2] - mu * ws0z) * isig;
        o0.w = (acc[i][3] - mu * ws0w) * isig;
        o1.x = (acc[i][4] - mu * ws1x) * isig;
        o1.y = (acc[i][5] - mu * ws1y) * isig;
        o1.z = (acc[i][6] - mu * ws1z) * isig;
        o1.w = (acc[i][7] - mu * ws1w) * isig;
        p1[i] = o0.x * a10.x + o0.y * a10.y + o0.z * a10.z + o0.w * a10.w +
                o1.x * a11.x + o1.y * a11.y + o1.z * a11.z + o1.w * a11.w;
        p2[i] = o0.x * a20.x + o0.y * a20.y + o0.z * a20.z + o0.w * a20.w +
                o1.x * a21.x + o1.y * a21.y + o1.z * a21.z + o1.w * a21.w;
        if (gr < NN) {
            uint4 pk;
            pk.x = ((u32)f2bf(o0.y) << 16) | f2bf(o0.x);
            pk.y = ((u32)f2bf(o0.w) << 16) | f2bf(o0.z);
            pk.z = ((u32)f2bf(o1.y) << 16) | f2bf(o1.x);
            pk.w = ((u32)f2bf(o1.w) << 16) | f2bf(o1.z);
            *reinterpret_cast<uint4*>(&zbf[gr * 64 + tcol * 4]) = pk;
        }
    }
    // reduce p1/p2 across the 16 tcol lanes (same trow group)
    #pragma unroll
    for (int d = 8; d; d >>= 1) {
        #pragma unroll
        for (int i = 0; i < 8; ++i) {
            p1[i] += __shfl_down(p1[i], d, 16);
            p2[i] += __shfl_down(p2[i], d, 16);
        }
    }
    if (tcol == 0) {
        #pragma unroll
        for (int i = 0; i < 8; ++i) {
            int gr = row0 + trow * 8 + i;
            if (gr < NN) { s1[gr] = p1[i]; s2[gr] = p2[i]; }
        }
    }
}

// --- aggregate: lane-parallel h, 8-deep batched gathers, register pool ---
__global__ __launch_bounds__(256) void k_aggregate(const u32* __restrict__ zbf,
                                                   const float* __restrict__ s1,
                                                   const float* __restrict__ s2,
                                                   const int* __restrict__ off,
                                                   const int* __restrict__ dst_s,
                                                   const int* __restrict__ idx,
                                                   float* __restrict__ pooled) {
    int wave = (blockIdx.x * 256 + threadIdx.x) >> 6;
    int lane = threadIdx.x & 63;
    int n0 = wave * KNODE;
    if (n0 >= NN) return;
    int n1 = n0 + KNODE;
    if (n1 > NN) n1 = NN;

    float pool0 = 0.f, pool1 = 0.f;
    int curg = idx[n0];

    for (int node = n0; node < n1; ++node) {
        int g = idx[node];
        if (g != curg) {
            atomicAdd(&pooled[curg * HH + lane * 2], pool0);
            atomicAdd(&pooled[curg * HH + lane * 2 + 1], pool1);
            pool0 = 0.f; pool1 = 0.f;
            curg = g;
        }
        int j0 = off[node], j1 = off[node + 1];
        float s1n = s1[node];
        float acc0 = 0.f, acc1 = 0.f, hsl = 0.f;

        for (int b = j0; b < j1; b += 64) {
            int cnt = j1 - b;
            if (cnt > 64) cnt = 64;
            // lane-parallel: lane l owns edge b+l
            int jj = b + ((lane < cnt) ? lane : 0);
            int dl = dst_s[jj];
            float ev = s1n + s2[dl];
            ev = (ev >= 0.f) ? ev : LRELU_A * ev;
            float hl = __expf(ev);
            if (lane >= cnt) hl = 0.f;
            hsl += hl;
            // broadcast loop, 8 loads in flight
            int k = 0;
            for (; k + 8 <= cnt; k += 8) {
                int dd[8]; float hh[8]; u32 uu[8];
                #pragma unroll
                for (int q = 0; q < 8; ++q) {
                    dd[q] = __shfl(dl, k + q);
                    hh[q] = __shfl(hl, k + q);
                }
                #pragma unroll
                for (int q = 0; q < 8; ++q) uu[q] = zbf[(dd[q] << 6) | lane];
                #pragma unroll
                for (int q = 0; q < 8; ++q) {
                    acc0 += hh[q] * __uint_as_float(uu[q] << 16);
                    acc1 += hh[q] * __uint_as_float(uu[q] & 0xFFFF0000u);
                }
            }
            for (; k + 4 <= cnt; k += 4) {
                int dd[4]; float hh[4]; u32 uu[4];
                #pragma unroll
                for (int q = 0; q < 4; ++q) {
                    dd[q] = __shfl(dl, k + q);
                    hh[q] = __shfl(hl, k + q);
                }
                #pragma unroll
                for (int q = 0; q < 4; ++q) uu[q] = zbf[(dd[q] << 6) | lane];
                #pragma unroll
                for (int q = 0; q < 4; ++q) {
                    acc0 += hh[q] * __uint_as_float(uu[q] << 16);
                    acc1 += hh[q] * __uint_as_float(uu[q] & 0xFFFF0000u);
                }
            }
            for (; k < cnt; ++k) {
                int dk = __shfl(dl, k);
                float hk = __shfl(hl, k);
                u32 u = zbf[(dk << 6) | lane];
                acc0 += hk * __uint_as_float(u << 16);
                acc1 += hk * __uint_as_float(u & 0xFFFF0000u);
            }
        }
        // wave-reduce the softmax denominator
        float hs = hsl;
        #pragma unroll
        for (int d = 32; d; d >>= 1) hs += __shfl_xor(hs, d);
        float inv = (hs > 0.f) ? 1.f / hs : 0.f;
        pool0 += fmaxf(acc0 * inv, 0.f);
        pool1 += fmaxf(acc1 * inv, 0.f);
    }
    atomicAdd(&pooled[curg * HH + lane * 2], pool0);
    atomicAdd(&pooled[curg * HH + lane * 2 + 1], pool1);
}

// ---------------- batchnorm stats -> scale/shift ----------------
__global__ __launch_bounds__(512) void k_bn(const float* __restrict__ pooled,
                                            const float* __restrict__ gamma,
                                            const float* __restrict__ beta,
                                            float* __restrict__ scale,
                                            float* __restrict__ shift) {
    __shared__ float sm[512], sm2[512];
    int f = threadIdx.x & 127, q = threadIdx.x >> 7;
    float s = 0.f, ss = 0.f;
    for (int g = q; g < GG; g += 4) {
        float v = pooled[g * HH + f];
        s += v;
        ss += v * v;
    }
    sm[threadIdx.x] = s;
    sm2[threadIdx.x] = ss;
    __syncthreads();
    if (q == 0) {
        s  = sm[f] + sm[f + 128] + sm[f + 256] + sm[f + 384];
        ss = sm2[f] + sm2[f + 128] + sm2[f + 256] + sm2[f + 384];
        float mean = s / GG;
        float var  = ss / GG - mean * mean;  // biased (jnp.var default)
        float sc = gamma[f] * rsqrtf(var + BN_EPS);
        scale[f] = sc;
        shift[f] = beta[f] - mean * sc;
    }
}

// ---------------- head: BN affine -> fc1+relu -> fc2 -> log_softmax --------
__global__ __launch_bounds__(128) void k_head(const float* __restrict__ pooled,
                                              const float* __restrict__ scale,
                                              const float* __restrict__ shift,
                                              const float* __restrict__ fc1w,
                                              const float* __restrict__ fc1b,
                                              const float* __restrict__ fc2w,
                                              const float* __restrict__ fc2b,
                                              float* __restrict__ out) {
    __shared__ __align__(16) float xb[128];
    __shared__ __align__(16) float h1[128];
    __shared__ float lg[16];
    int g = blockIdx.x;
    int t = threadIdx.x;
    xb[t] = pooled[g * HH + t] * scale[t] + shift[t];
    __syncthreads();
    float acc = 0.f;
    const float4* wr = reinterpret_cast<const float4*>(&fc1w[t * HH]);
    #pragma unroll 8
    for (int k = 0; k < 32; ++k) {
        float4 w4 = wr[k];
        float4 xv = *reinterpret_cast<const float4*>(&xb[k * 4]);
        acc += w4.x * xv.x + w4.y * xv.y + w4.z * xv.z + w4.w * xv.w;
    }
    acc += fc1b[t];
    h1[t] = (acc > 0.f) ? acc : 0.f;
    __syncthreads();
    if (t < CC) {
        float a = 0.f;
        const float4* w2 = reinterpret_cast<const float4*>(&fc2w[t * HH]);
        #pragma unroll 8
        for (int k = 0; k < 32; ++k) {
            float4 w4 = w2[k];
            float4 hv = *reinterpret_cast<const float4*>(&h1[k * 4]);
            a += w4.x * hv.x + w4.y * hv.y + w4.z * hv.z + w4.w * hv.w;
        }
        lg[t] = a + fc2b[t];
    }
    __syncthreads();
    if (t == 0) {
        float mx = lg[0];
        for (int c = 1; c < CC; ++c) mx = fmaxf(mx, lg[c]);
        float se = 0.f;
        for (int c = 0; c < CC; ++c) se += __expf(lg[c] - mx);
        float lse = mx + logf(se);
        for (int c = 0; c < CC; ++c) out[g * CC + c] = lg[c] - lse;
    }
}

// ---------------- launch ----------------
extern "C" void kernel_launch(void* const* d_in, const int* in_sizes, int n_in,
                              void* d_out, int out_size, void* d_ws, size_t ws_size,
                              hipStream_t stream) {
    const float* x_in  = (const float*)d_in[0];
    const int*   eidx  = (const int*)d_in[1];
    const int*   src   = eidx;
    const int*   dst   = eidx + NE;
    const int*   idx   = (const int*)d_in[2];
    const float* fc_w  = (const float*)d_in[3];
    const float* a1    = (const float*)d_in[4];
    const float* a2    = (const float*)d_in[5];
    const float* fc1w  = (const float*)d_in[6];
    const float* fc1b  = (const float*)d_in[7];
    const float* fc2w  = (const float*)d_in[8];
    const float* fc2b  = (const float*)d_in[9];
    const float* gamma = (const float*)d_in[10];
    const float* beta  = (const float*)d_in[11];
    float* out = (float*)d_out;

    char* p = (char*)d_ws;
    auto alloc = [&](size_t bytes) {
        char* r = p;
        p += (bytes + 255) & ~(size_t)255;
        return r;
    };
    double* st     = (double*)alloc(4 * sizeof(double));
    float*  wsum   = (float*)alloc(HH * sizeof(float));
    float*  musig  = (float*)alloc(4 * sizeof(float));
    float*  scale  = (float*)alloc(HH * sizeof(float));
    float*  shift  = (float*)alloc(HH * sizeof(float));
    float*  wt     = (float*)alloc((size_t)DD * HH * sizeof(float));
    u16*    cnt_b  = (u16*)alloc((size_t)TT * NB * sizeof(u16));
    u16*    rel_b  = (u16*)alloc((size_t)TT * NB * sizeof(u16));
    u8*     rank_e = (u8*)alloc((size_t)NE * sizeof(u8));
    int*    base_b = (int*)alloc((NB + 1) * sizeof(int));
    u32*    ebuf   = (u32*)alloc((size_t)NE * sizeof(u32));
    int*    off    = (int*)alloc((NN + 1) * sizeof(int));
    int*    dst_s  = (int*)alloc((size_t)NE * sizeof(int));
    u32*    zbf    = (u32*)alloc((size_t)NN * (HH / 2) * sizeof(u32));
    float*  s1     = (float*)alloc(NN * sizeof(float));
    float*  s2     = (float*)alloc(NN * sizeof(float));
    float*  pooled = (float*)alloc((size_t)GG * HH * sizeof(float));

    hipMemsetAsync(st, 0, 4 * sizeof(double), stream);
    hipMemsetAsync(pooled, 0, (size_t)GG * HH * sizeof(float), stream);

    k_stats<<<1024, 256, 0, stream>>>(x_in, st);
    k_prep<<<1, 256, 0, stream>>>(fc_w, st, wsum, musig, wt);
    k_bcount<<<TT, 256, 0, stream>>>(src, cnt_b, rank_e);
    k_brel<<<1, 256, 0, stream>>>(cnt_b, rel_b, base_b);
    k_gemm<<<(NN + 127) / 128, 256, 0, stream>>>(x_in, wt, wsum, musig, a1, a2,
                                                 zbf, s1, s2);
    k_bscat<<<TT, 256, 0, stream>>>(src, dst, rel_b, rank_e, base_b, ebuf);
    k_bcsr<<<NB, 256, 0, stream>>>(ebuf, base_b, off, dst_s);
    int nwaves = (NN + KNODE - 1) / KNODE;          // 6250
    int nblocks = (nwaves + 3) / 4;                 // 4 waves per 256-thr block
    k_aggregate<<<nblocks, 256, 0, stream>>>(zbf, s1, s2, off, dst_s, idx, pooled);
    k_bn<<<1, 512, 0, stream>>>(pooled, gamma, beta, scale, shift);
    k_head<<<GG, 128, 0, stream>>>(pooled, scale, shift, fc1w, fc1b, fc2w, fc2b, out);
}

// Round 12
// 174.017 us; speedup vs baseline: 1.5066x; 1.3715x over previous
//
#include <hip/hip_runtime.h>

#define NN 50000
#define NE 1600000
#define DD 128
#define HH 128
#define CC 10
#define GG 512
#define LRELU_A 0.05f
#define BN_EPS 1e-5f

#define TT 256          // edge tiles
#define EPT (NE / TT)   // 6250 edges per tile
#define NB 196          // src buckets (256 consecutive nodes each)
#define NPB 256         // nodes per bucket
#define KNODE 8         // nodes per wave in aggregate
#define STB 1024        // stats blocks

typedef unsigned int u32;
typedef unsigned short u16;
typedef unsigned char u8;

__device__ __forceinline__ u16 f2bf(float f) {
    u32 u = __float_as_uint(f);
    u32 r = u + 0x7FFFu + ((u >> 16) & 1u);
    return (u16)(r >> 16);
}

// ---- k_front: blocks 0..255 = bucket histogram + zero pooled;
//               blocks 256..1279 = x stats partials (no atomics) ----
__global__ __launch_bounds__(256) void k_front(const int* __restrict__ src,
                                               const float* __restrict__ x,
                                               u16* __restrict__ cnt_b,
                                               u8* __restrict__ rank_e,
                                               float* __restrict__ pooled,
                                               double* __restrict__ pst) {
    __shared__ u32 h[NB];
    __shared__ double ls[4], lss[4];
    int bid = blockIdx.x, tid = threadIdx.x;
    if (bid < TT) {
        for (int i = tid; i < NB; i += 256) h[i] = 0;
        pooled[bid * 256 + tid] = 0.f;   // GG*HH == 256*256
        __syncthreads();
        int e0 = bid * EPT;
        for (int i = tid; i < EPT; i += 256) {
            int b = src[e0 + i] >> 8;
            u32 old = atomicAdd(&h[b], 1u);
            rank_e[e0 + i] = (u8)old;
        }
        __syncthreads();
        for (int i = tid; i < NB; i += 256) cnt_b[bid * NB + i] = (u16)h[i];
    } else {
        int sb = bid - TT;
        const int M4 = NN * DD / 4;
        double s = 0.0, ss = 0.0;
        for (int i = sb * 256 + tid; i < M4; i += STB * 256) {
            float4 v = reinterpret_cast<const float4*>(x)[i];
            s  += (double)v.x + (double)v.y + (double)v.z + (double)v.w;
            ss += (double)v.x * v.x + (double)v.y * v.y + (double)v.z * v.z +
                  (double)v.w * v.w;
        }
        for (int d = 32; d; d >>= 1) { s += __shfl_down(s, d); ss += __shfl_down(ss, d); }
        int lane = tid & 63, w = tid >> 6;
        if (lane == 0) { ls[w] = s; lss[w] = ss; }
        __syncthreads();
        if (tid == 0) {
            pst[2 * sb]     = ls[0] + ls[1] + ls[2] + ls[3];
            pst[2 * sb + 1] = lss[0] + lss[1] + lss[2] + lss[3];
        }
    }
}

// ---- k_mid: block 0 = brel (tile prefix + bucket bases);
//             block 1 = stats reduce -> musig, wsum, wt transpose ----
__global__ __launch_bounds__(256) void k_mid(const u16* __restrict__ cnt_b,
                                             const double* __restrict__ pst,
                                             const float* __restrict__ fc_w,
                                             u16* __restrict__ rel_b,
                                             int* __restrict__ base_b,
                                             float* __restrict__ wsum,
                                             float* __restrict__ musig,
                                             float* __restrict__ wt) {
    int t = threadIdx.x;
    if (blockIdx.x == 0) {
        __shared__ int sm[256];
        int b = t;
        int run = 0;
        if (b < NB) {
            for (int tt = 0; tt < TT; ++tt) {
                int c = cnt_b[tt * NB + b];
                rel_b[tt * NB + b] = (u16)run;
                run += c;
            }
        }
        sm[b] = (b < NB) ? run : 0;
        __syncthreads();
        int v = sm[b];
        for (int d = 1; d < 256; d <<= 1) {
            int x = 0;
            if (b >= d) x = sm[b - d];
            __syncthreads();
            if (b >= d) sm[b] += x;
            __syncthreads();
        }
        if (b < NB) base_b[b] = sm[b] - v;
        if (b == NB - 1) base_b[NB] = sm[b];
    } else {
        __shared__ double rs[256], rss[256];
        double s  = pst[2 * t] + pst[2 * (t + 256)] + pst[2 * (t + 512)] + pst[2 * (t + 768)];
        double ss = pst[2 * t + 1] + pst[2 * (t + 256) + 1] +
                    pst[2 * (t + 512) + 1] + pst[2 * (t + 768) + 1];
        rs[t] = s; rss[t] = ss;
        __syncthreads();
        for (int d = 128; d; d >>= 1) {
            if (t < d) { rs[t] += rs[t + d]; rss[t] += rss[t + d]; }
            __syncthreads();
        }
        if (t == 0) {
            double M = (double)NN * DD;
            double mean = rs[0] / M;
            double var  = (rss[0] - rs[0] * rs[0] / M) / (M - 1.0);  // ddof=1
            musig[0] = (float)mean;
            musig[1] = (float)(1.0 / sqrt(var));
        }
        if (t < 128) {
            float acc = 0.f;
            for (int k = 0; k < DD; ++k) acc += fc_w[t * DD + k];
            wsum[t] = acc;
        }
        for (int i = t; i < DD * HH; i += 256) {
            int k = i >> 7, c = i & 127;
            wt[i] = fc_w[c * DD + k];
        }
    }
}

// ---- k_big: blocks 0..255 = bscat; blocks 256.. = gemm (fused z/zbf/s1/s2) ----
#define PADX 132
__global__ __launch_bounds__(256, 2) void k_big(const int* __restrict__ src,
                                                const int* __restrict__ dst,
                                                const u16* __restrict__ rel_b,
                                                const u8* __restrict__ rank_e,
                                                const int* __restrict__ base_b,
                                                u32* __restrict__ ebuf,
                                                const float* __restrict__ x,
                                                const float* __restrict__ wt,
                                                const float* __restrict__ wsum,
                                                const float* __restrict__ musig,
                                                const float* __restrict__ a1,
                                                const float* __restrict__ a2,
                                                u32* __restrict__ zbf,
                                                float* __restrict__ s1,
                                                float* __restrict__ s2) {
    __shared__ float xs[128][PADX];  // ~67.6 KB -> 2 blocks/CU
    int bid = blockIdx.x, tid = threadIdx.x;

    if (bid < TT) {
        int e0 = bid * EPT;
        for (int i = tid; i < EPT; i += 256) {
            int s = src[e0 + i];
            int b = s >> 8;
            int pos = base_b[b] + (int)rel_b[bid * NB + b] + (int)rank_e[e0 + i];
            ebuf[pos] = ((u32)dst[e0 + i] << 8) | (u32)(s & 255);
        }
        return;
    }

    int row0 = (bid - TT) * 128;
    for (int i = tid; i < 128 * 32; i += 256) {
        int r = i >> 5;
        int m = i & 31;
        int gr = row0 + r;
        float4 v = (gr < NN) ? reinterpret_cast<const float4*>(x)[gr * 32 + m]
                             : make_float4(0.f, 0.f, 0.f, 0.f);
        *reinterpret_cast<float4*>(&xs[r][m << 2]) = v;
    }
    __syncthreads();

    int trow = tid >> 4, tcol = tid & 15;  // 16 row-groups x 8 rows
    float acc[8][8];
    #pragma unroll
    for (int i = 0; i < 8; ++i)
        #pragma unroll
        for (int j = 0; j < 8; ++j) acc[i][j] = 0.f;

    const float4* wt4 = reinterpret_cast<const float4*>(wt);
    for (int k = 0; k < 128; k += 4) {
        float4 xv[8];
        #pragma unroll
        for (int i = 0; i < 8; ++i)
            xv[i] = *reinterpret_cast<const float4*>(&xs[trow * 8 + i][k]);
        #pragma unroll
        for (int kk = 0; kk < 4; ++kk) {
            float4 w0 = wt4[(k + kk) * 32 + tcol * 2];
            float4 w1 = wt4[(k + kk) * 32 + tcol * 2 + 1];
            #pragma unroll
            for (int i = 0; i < 8; ++i) {
                float a = (kk == 0) ? xv[i].x
                        : (kk == 1) ? xv[i].y
                        : (kk == 2) ? xv[i].z : xv[i].w;
                acc[i][0] += a * w0.x; acc[i][1] += a * w0.y;
                acc[i][2] += a * w0.z; acc[i][3] += a * w0.w;
                acc[i][4] += a * w1.x; acc[i][5] += a * w1.y;
                acc[i][6] += a * w1.z; acc[i][7] += a * w1.w;
            }
        }
    }

    float mu = musig[0], isig = musig[1];
    int c0 = tcol * 8;
    float4 a10 = *reinterpret_cast<const float4*>(&a1[c0]);
    float4 a11 = *reinterpret_cast<const float4*>(&a1[c0 + 4]);
    float4 a20 = *reinterpret_cast<const float4*>(&a2[c0]);
    float4 a21 = *reinterpret_cast<const float4*>(&a2[c0 + 4]);
    float ws0x = wsum[c0 + 0], ws0y = wsum[c0 + 1], ws0z = wsum[c0 + 2], ws0w = wsum[c0 + 3];
    float ws1x = wsum[c0 + 4], ws1y = wsum[c0 + 5], ws1z = wsum[c0 + 6], ws1w = wsum[c0 + 7];

    float p1[8], p2[8];
    #pragma unroll
    for (int i = 0; i < 8; ++i) {
        int gr = row0 + trow * 8 + i;
        float4 o0, o1;
        o0.x = (acc[i][0] - mu * ws0x) * isig;
        o0.y = (acc[i][1] - mu * ws0y) * isig;
        o0.z = (acc[i][2] - mu * ws0z) * isig;
        o0.w = (acc[i][3] - mu * ws0w) * isig;
        o1.x = (acc[i][4] - mu * ws1x) * isig;
        o1.y = (acc[i][5] - mu * ws1y) * isig;
        o1.z = (acc[i][6] - mu * ws1z) * isig;
        o1.w = (acc[i][7] - mu * ws1w) * isig;
        p1[i] = o0.x * a10.x + o0.y * a10.y + o0.z * a10.z + o0.w * a10.w +
                o1.x * a11.x + o1.y * a11.y + o1.z * a11.z + o1.w * a11.w;
        p2[i] = o0.x * a20.x + o0.y * a20.y + o0.z * a20.z + o0.w * a20.w +
                o1.x * a21.x + o1.y * a21.y + o1.z * a21.z + o1.w * a21.w;
        if (gr < NN) {
            uint4 pk;
            pk.x = ((u32)f2bf(o0.y) << 16) | f2bf(o0.x);
            pk.y = ((u32)f2bf(o0.w) << 16) | f2bf(o0.z);
            pk.z = ((u32)f2bf(o1.y) << 16) | f2bf(o1.x);
            pk.w = ((u32)f2bf(o1.w) << 16) | f2bf(o1.z);
            *reinterpret_cast<uint4*>(&zbf[gr * 64 + tcol * 4]) = pk;
        }
    }
    #pragma unroll
    for (int d = 8; d; d >>= 1) {
        #pragma unroll
        for (int i = 0; i < 8; ++i) {
            p1[i] += __shfl_down(p1[i], d, 16);
            p2[i] += __shfl_down(p2[i], d, 16);
        }
    }
    if (tcol == 0) {
        #pragma unroll
        for (int i = 0; i < 8; ++i) {
            int gr = row0 + trow * 8 + i;
            if (gr < NN) { s1[gr] = p1[i]; s2[gr] = p2[i]; }
        }
    }
}

// ---- k_bcsr: per-bucket counting sort -> off[]; emits packed (dst<<16)|h_bf16 ----
__global__ __launch_bounds__(256) void k_bcsr(const u32* __restrict__ ebuf,
                                              const int* __restrict__ base_b,
                                              const float* __restrict__ s1,
                                              const float* __restrict__ s2,
                                              int* __restrict__ off,
                                              u32* __restrict__ dst_s) {
    __shared__ u32 hist[NPB];
    __shared__ u32 cur[NPB];
    __shared__ int sm[256];
    int b = blockIdx.x, tid = threadIdx.x;
    int ebase = base_b[b], eend = base_b[b + 1];
    int m = eend - ebase;
    hist[tid] = 0;
    __syncthreads();
    for (int i = tid; i < m; i += 256)
        atomicAdd(&hist[ebuf[ebase + i] & 255u], 1u);
    __syncthreads();
    int v = (int)hist[tid];
    sm[tid] = v;
    __syncthreads();
    for (int d = 1; d < 256; d <<= 1) {
        int x = 0;
        if (tid >= d) x = sm[tid - d];
        __syncthreads();
        if (tid >= d) sm[tid] += x;
        __syncthreads();
    }
    int st = sm[tid] - v;
    cur[tid] = (u32)st;
    int n = b * NPB + tid;
    if (n < NN) off[n] = ebase + st;
    if (b == NB - 1 && tid == 0) off[NN] = NE;
    __syncthreads();
    for (int i = tid; i < m; i += 256) {
        u32 e = ebuf[ebase + i];
        int ls = (int)(e & 255u);
        int dn = (int)(e >> 8);
        int p = (int)atomicAdd(&cur[ls], 1u);
        float ev = s1[b * NPB + ls] + s2[dn];
        ev = (ev >= 0.f) ? ev : LRELU_A * ev;
        float h = __expf(ev);
        dst_s[ebase + p] = ((u32)dn << 16) | (u32)f2bf(h);
    }
}

// ---- aggregate: packed (dst|h) edges, 8-deep batched gathers, register pool ----
__global__ __launch_bounds__(256) void k_aggregate(const u32* __restrict__ zbf,
                                                   const int* __restrict__ off,
                                                   const u32* __restrict__ dst_s,
                                                   const int* __restrict__ idx,
                                                   float* __restrict__ pooled) {
    int wave = (blockIdx.x * 256 + threadIdx.x) >> 6;
    int lane = threadIdx.x & 63;
    int n0 = wave * KNODE;
    if (n0 >= NN) return;
    int n1 = n0 + KNODE;
    if (n1 > NN) n1 = NN;

    float pool0 = 0.f, pool1 = 0.f;
    int curg = idx[n0];

    for (int node = n0; node < n1; ++node) {
        int g = idx[node];
        if (g != curg) {
            atomicAdd(&pooled[curg * HH + lane * 2], pool0);
            atomicAdd(&pooled[curg * HH + lane * 2 + 1], pool1);
            pool0 = 0.f; pool1 = 0.f;
            curg = g;
        }
        int j0 = off[node], j1 = off[node + 1];
        float acc0 = 0.f, acc1 = 0.f, hsl = 0.f;

        for (int b = j0; b < j1; b += 64) {
            int cnt = j1 - b;
            if (cnt > 64) cnt = 64;
            int jj = b + ((lane < cnt) ? lane : 0);
            int ul = (int)dst_s[jj];
            if (lane < cnt) hsl += __uint_as_float((u32)ul << 16);
            int k = 0;
            for (; k + 8 <= cnt; k += 8) {
                int eu[8]; u32 uu[8];
                #pragma unroll
                for (int q = 0; q < 8; ++q) eu[q] = __shfl(ul, k + q);
                #pragma unroll
                for (int q = 0; q < 8; ++q)
                    uu[q] = zbf[(((u32)eu[q] >> 16) << 6) | lane];
                #pragma unroll
                for (int q = 0; q < 8; ++q) {
                    float hq = __uint_as_float((u32)eu[q] << 16);
                    acc0 += hq * __uint_as_float(uu[q] << 16);
                    acc1 += hq * __uint_as_float(uu[q] & 0xFFFF0000u);
                }
            }
            for (; k + 4 <= cnt; k += 4) {
                int eu[4]; u32 uu[4];
                #pragma unroll
                for (int q = 0; q < 4; ++q) eu[q] = __shfl(ul, k + q);
                #pragma unroll
                for (int q = 0; q < 4; ++q)
                    uu[q] = zbf[(((u32)eu[q] >> 16) << 6) | lane];
                #pragma unroll
                for (int q = 0; q < 4; ++q) {
                    float hq = __uint_as_float((u32)eu[q] << 16);
                    acc0 += hq * __uint_as_float(uu[q] << 16);
                    acc1 += hq * __uint_as_float(uu[q] & 0xFFFF0000u);
                }
            }
            for (; k < cnt; ++k) {
                int e = __shfl(ul, k);
                float hk = __uint_as_float((u32)e << 16);
                u32 u = zbf[(((u32)e >> 16) << 6) | lane];
                acc0 += hk * __uint_as_float(u << 16);
                acc1 += hk * __uint_as_float(u & 0xFFFF0000u);
            }
        }
        float hs = hsl;
        #pragma unroll
        for (int d = 32; d; d >>= 1) hs += __shfl_xor(hs, d);
        float inv = (hs > 0.f) ? 1.f / hs : 0.f;
        pool0 += fmaxf(acc0 * inv, 0.f);
        pool1 += fmaxf(acc1 * inv, 0.f);
    }
    atomicAdd(&pooled[curg * HH + lane * 2], pool0);
    atomicAdd(&pooled[curg * HH + lane * 2 + 1], pool1);
}

// ---- head: per-block BN stats (pooled is L2-hot) -> fc1 -> fc2 -> log_softmax ----
__global__ __launch_bounds__(128) void k_head(const float* __restrict__ pooled,
                                              const float* __restrict__ gamma,
                                              const float* __restrict__ beta,
                                              const float* __restrict__ fc1w,
                                              const float* __restrict__ fc1b,
                                              const float* __restrict__ fc2w,
                                              const float* __restrict__ fc2b,
                                              float* __restrict__ out) {
    __shared__ __align__(16) float xb[128];
    __shared__ __align__(16) float h1[128];
    __shared__ float lg[16];
    int g = blockIdx.x;
    int t = threadIdx.x;
    float s = 0.f, ss = 0.f;
    #pragma unroll 8
    for (int q = 0; q < GG; ++q) {
        float v = pooled[q * HH + t];
        s += v;
        ss += v * v;
    }
    float mean = s / GG;
    float var  = ss / GG - mean * mean;  // biased
    float sc = gamma[t] * rsqrtf(var + BN_EPS);
    xb[t] = pooled[g * HH + t] * sc + (beta[t] - mean * sc);
    __syncthreads();
    float acc = 0.f;
    const float4* wr = reinterpret_cast<const float4*>(&fc1w[t * HH]);
    #pragma unroll 8
    for (int k = 0; k < 32; ++k) {
        float4 w4 = wr[k];
        float4 xv = *reinterpret_cast<const float4*>(&xb[k * 4]);
        acc += w4.x * xv.x + w4.y * xv.y + w4.z * xv.z + w4.w * xv.w;
    }
    acc += fc1b[t];
    h1[t] = (acc > 0.f) ? acc : 0.f;
    __syncthreads();
    if (t < CC) {
        float a = 0.f;
        const float4* w2 = reinterpret_cast<const float4*>(&fc2w[t * HH]);
        #pragma unroll 8
        for (int k = 0; k < 32; ++k) {
            float4 w4 = w2[k];
            float4 hv = *reinterpret_cast<const float4*>(&h1[k * 4]);
            a += w4.x * hv.x + w4.y * hv.y + w4.z * hv.z + w4.w * hv.w;
        }
        lg[t] = a + fc2b[t];
    }
    __syncthreads();
    if (t == 0) {
        float mx = lg[0];
        for (int c = 1; c < CC; ++c) mx = fmaxf(mx, lg[c]);
        float se = 0.f;
        for (int c = 0; c < CC; ++c) se += __expf(lg[c] - mx);
        float lse = mx + logf(se);
        for (int c = 0; c < CC; ++c) out[g * CC + c] = lg[c] - lse;
    }
}

// ---------------- launch ----------------
extern "C" void kernel_launch(void* const* d_in, const int* in_sizes, int n_in,
                              void* d_out, int out_size, void* d_ws, size_t ws_size,
                              hipStream_t stream) {
    const float* x_in  = (const float*)d_in[0];
    const int*   eidx  = (const int*)d_in[1];
    const int*   src   = eidx;
    const int*   dst   = eidx + NE;
    const int*   idx   = (const int*)d_in[2];
    const float* fc_w  = (const float*)d_in[3];
    const float* a1    = (const float*)d_in[4];
    const float* a2    = (const float*)d_in[5];
    const float* fc1w  = (const float*)d_in[6];
    const float* fc1b  = (const float*)d_in[7];
    const float* fc2w  = (const float*)d_in[8];
    const float* fc2b  = (const float*)d_in[9];
    const float* gamma = (const float*)d_in[10];
    const float* beta  = (const float*)d_in[11];
    float* out = (float*)d_out;

    char* p = (char*)d_ws;
    auto alloc = [&](size_t bytes) {
        char* r = p;
        p += (bytes + 255) & ~(size_t)255;
        return r;
    };
    double* pst    = (double*)alloc((size_t)STB * 2 * sizeof(double));
    float*  wsum   = (float*)alloc(HH * sizeof(float));
    float*  musig  = (float*)alloc(4 * sizeof(float));
    float*  wt     = (float*)alloc((size_t)DD * HH * sizeof(float));
    u16*    cnt_b  = (u16*)alloc((size_t)TT * NB * sizeof(u16));
    u16*    rel_b  = (u16*)alloc((size_t)TT * NB * sizeof(u16));
    u8*     rank_e = (u8*)alloc((size_t)NE * sizeof(u8));
    int*    base_b = (int*)alloc((NB + 1) * sizeof(int));
    u32*    ebuf   = (u32*)alloc((size_t)NE * sizeof(u32));
    int*    off    = (int*)alloc((NN + 1) * sizeof(int));
    u32*    dst_s  = (u32*)alloc((size_t)NE * sizeof(u32));
    u32*    zbf    = (u32*)alloc((size_t)NN * (HH / 2) * sizeof(u32));
    float*  s1     = (float*)alloc(NN * sizeof(float));
    float*  s2     = (float*)alloc(NN * sizeof(float));
    float*  pooled = (float*)alloc((size_t)GG * HH * sizeof(float));

    k_front<<<TT + STB, 256, 0, stream>>>(src, x_in, cnt_b, rank_e, pooled, pst);
    k_mid<<<2, 256, 0, stream>>>(cnt_b, pst, fc_w, rel_b, base_b, wsum, musig, wt);
    int gemm_blocks = (NN + 127) / 128;  // 391
    k_big<<<TT + gemm_blocks, 256, 0, stream>>>(src, dst, rel_b, rank_e, base_b,
                                                ebuf, x_in, wt, wsum, musig,
                                                a1, a2, zbf, s1, s2);
    k_bcsr<<<NB, 256, 0, stream>>>(ebuf, base_b, s1, s2, off, dst_s);
    int nwaves = (NN + KNODE - 1) / KNODE;          // 6250
    int nblocks = (nwaves + 3) / 4;                 // 4 waves per 256-thr block
    k_aggregate<<<nblocks, 256, 0, stream>>>(zbf, off, dst_s, idx, pooled);
    k_head<<<GG, 128, 0, stream>>>(pooled, gamma, beta, fc1w, fc1b, fc2w, fc2b, out);
}